// Round 1
// baseline (4497.586 us; speedup 1.0000x reference)
//
#include <hip/hip_runtime.h>
#include <math.h>

#define T_LEN 1024
#define D_H 512
#define ND 2048
#define E_N 16
#define KEXP 15
#define DFFN 828
#define BT_TOT 2048  // B*T

__device__ __forceinline__ float sigmoidf_(float x) { return 1.f / (1.f + expf(-x)); }

// ---------------- zero fill ----------------
__global__ void zero_kernel(float* __restrict__ p, int n) {
    int i = blockIdx.x * blockDim.x + threadIdx.x;
    if (i < n) p[i] = 0.f;
}

// ---------------- router: gate_moe + route_lp ----------------
__global__ __launch_bounds__(64) void router_kernel(
    const float* __restrict__ stream, const float* __restrict__ rw,
    float* __restrict__ gate_out, float* __restrict__ lp_out)
{
    int bt = blockIdx.x; int b = bt >> 10; int t = bt & 1023;
    int lane = threadIdx.x;
    float ri[8];
#pragma unroll
    for (int w = 0; w < 8; ++w) {
        int d = lane + w * 64;
        float s = 0.f;
#pragma unroll
        for (int n = 0; n < 4; ++n)
            s += stream[(((size_t)b * 4 + n) * T_LEN + t) * D_H + d];
        ri[w] = 0.25f * s;
    }
    float logits[16];
    for (int e = 0; e < 16; ++e) {
        float p = 0.f;
#pragma unroll
        for (int w = 0; w < 8; ++w) p += ri[w] * rw[e * D_H + lane + w * 64];
#pragma unroll
        for (int off = 32; off; off >>= 1) p += __shfl_xor(p, off, 64);
        logits[e] = p;
    }
    float mx = logits[0];
    for (int e = 1; e < 16; ++e) mx = fmaxf(mx, logits[e]);
    float pr[16]; float sum = 0.f;
    for (int e = 0; e < 16; ++e) { pr[e] = expf(logits[e] - mx); sum += pr[e]; }
    float inv = 1.f / sum;
    for (int e = 0; e < 16; ++e) pr[e] *= inv;

    // top-prob / max-k selection (stable descending order)
    float gate[16]; bool taken[16];
    for (int e = 0; e < 16; ++e) { gate[e] = 0.f; taken[e] = false; }
    float prefix = 0.f;
    for (int rank = 0; rank < 4; ++rank) {
        int best = -1; float bp = -1.f;
        for (int e = 0; e < 16; ++e)
            if (!taken[e] && pr[e] > bp) { bp = pr[e]; best = e; }
        taken[best] = true;
        bool sel = (rank == 0) || (prefix < 0.8f);
        if (sel) gate[best] = bp;
        prefix += bp;
        if (!sel) break;
    }
    float lp = 0.f;
    for (int e = 0; e < 16; ++e)
        if (gate[e] > 0.f) lp += fmaxf(logf(pr[e]), -10.f);
    if (lane < 16) gate_out[(size_t)bt * 16 + lane] = gate[lane];
    if (lane == 0) lp_out[bt] = lp;
}

// ---------------- xn = rmsnorm(x) over nd=2048 ----------------
__global__ __launch_bounds__(256) void xn_kernel(
    const float* __restrict__ stream, float* __restrict__ xn)
{
    int bt = blockIdx.x; int b = bt >> 10; int t = bt & 1023;
    int tid = threadIdx.x;
    float v[8]; float ss = 0.f;
#pragma unroll
    for (int w = 0; w < 8; ++w) {
        int j = tid + w * 256;
        int n = j >> 9, d = j & 511;
        float x = stream[(((size_t)b * 4 + n) * T_LEN + t) * D_H + d];
        v[w] = x; ss += x * x;
    }
#pragma unroll
    for (int off = 32; off; off >>= 1) ss += __shfl_down(ss, off, 64);
    __shared__ float red[4];
    int wave = tid >> 6, lane = tid & 63;
    if (lane == 0) red[wave] = ss;
    __syncthreads();
    float tot = red[0] + red[1] + red[2] + red[3];
    float r = rsqrtf(tot / (float)ND + 1e-8f);
#pragma unroll
    for (int w = 0; w < 8; ++w)
        xn[(size_t)bt * ND + tid + w * 256] = v[w] * r;
}

// ---------------- MHC per expert: H_pre/H_post/H_res(sinkhorn) + h ----------------
__global__ __launch_bounds__(256) void mhc_kernel(
    const float* __restrict__ stream, const float* __restrict__ xn,
    const float* __restrict__ norm_w, const float* __restrict__ phi_pre,
    const float* __restrict__ phi_post, const float* __restrict__ phi_res,
    const float* __restrict__ b_pre, const float* __restrict__ b_post,
    const float* __restrict__ b_res, const float* __restrict__ alpha_pre,
    const float* __restrict__ alpha_post, const float* __restrict__ alpha_res,
    const float* __restrict__ swiglu_norm,
    float* __restrict__ h_out, float* __restrict__ Hpost_out, float* __restrict__ Hres_out,
    int k)
{
    int bt = blockIdx.x; int b = bt >> 10; int t = bt & 1023;
    int e = k + 1;
    int tid = threadIdx.x;
    float pre[4] = {0,0,0,0}, post[4] = {0,0,0,0};
    float res[16] = {0,0,0,0,0,0,0,0,0,0,0,0,0,0,0,0};
    const float* xr = xn + (size_t)bt * ND;
    const float* nw = norm_w + (size_t)e * ND;
    const float* pp = phi_pre + (size_t)e * 4 * ND;
    const float* pq = phi_post + (size_t)e * 4 * ND;
    const float* prr = phi_res + (size_t)e * 16 * ND;
#pragma unroll
    for (int w = 0; w < 8; ++w) {
        int j = tid + w * 256;
        float y = xr[j] * nw[j];
#pragma unroll
        for (int n = 0; n < 4; ++n) { pre[n] += y * pp[n * ND + j]; post[n] += y * pq[n * ND + j]; }
#pragma unroll
        for (int n = 0; n < 16; ++n) res[n] += y * prr[n * ND + j];
    }
#pragma unroll
    for (int off = 32; off; off >>= 1) {
#pragma unroll
        for (int n = 0; n < 4; ++n) {
            pre[n] += __shfl_down(pre[n], off, 64);
            post[n] += __shfl_down(post[n], off, 64);
        }
#pragma unroll
        for (int n = 0; n < 16; ++n) res[n] += __shfl_down(res[n], off, 64);
    }
    __shared__ float red[4][24];
    __shared__ float Hpre_s[4], Hpost_s[4], Hres_s[16];
    int wave = tid >> 6, lane = tid & 63;
    if (lane == 0) {
        for (int n = 0; n < 4; ++n) { red[wave][n] = pre[n]; red[wave][4 + n] = post[n]; }
        for (int n = 0; n < 16; ++n) red[wave][8 + n] = res[n];
    }
    __syncthreads();
    if (tid == 0) {
        float s[24];
        for (int i = 0; i < 24; ++i) s[i] = red[0][i] + red[1][i] + red[2][i] + red[3][i];
        float ap = alpha_pre[e], aq = alpha_post[e], ar = alpha_res[e];
        for (int n = 0; n < 4; ++n) Hpre_s[n] = sigmoidf_(ap * s[n] + b_pre[e * 4 + n]);
        for (int n = 0; n < 4; ++n) Hpost_s[n] = 2.f * sigmoidf_(aq * s[4 + n] + b_post[e * 4 + n]);
        float M[16];
        for (int i = 0; i < 16; ++i) M[i] = expf(ar * s[8 + i] + b_res[e * 16 + i]);
        for (int it = 0; it < 6; ++it) {
            for (int i = 0; i < 4; ++i) {
                float rs = M[i*4] + M[i*4+1] + M[i*4+2] + M[i*4+3];
                float iv = 1.f / rs;
                for (int j = 0; j < 4; ++j) M[i*4+j] *= iv;
            }
            for (int j = 0; j < 4; ++j) {
                float cs = M[j] + M[4+j] + M[8+j] + M[12+j];
                float iv = 1.f / cs;
                for (int i = 0; i < 4; ++i) M[i*4+j] *= iv;
            }
        }
        for (int i = 0; i < 16; ++i) Hres_s[i] = M[i];
    }
    __syncthreads();
    if (tid < 4) Hpost_out[((size_t)k * BT_TOT + bt) * 4 + tid] = Hpost_s[tid];
    if (tid < 16) Hres_out[((size_t)k * BT_TOT + bt) * 16 + tid] = Hres_s[tid];
    // h_e = H_pre @ stream rows; rms; * swiglu_norm
    float he[2]; float ss = 0.f;
#pragma unroll
    for (int w = 0; w < 2; ++w) {
        int d = tid + w * 256;
        float v = 0.f;
#pragma unroll
        for (int n = 0; n < 4; ++n)
            v += Hpre_s[n] * stream[(((size_t)b * 4 + n) * T_LEN + t) * D_H + d];
        he[w] = v; ss += v * v;
    }
#pragma unroll
    for (int off = 32; off; off >>= 1) ss += __shfl_down(ss, off, 64);
    __shared__ float red2[4];
    if (lane == 0) red2[wave] = ss;
    __syncthreads();
    float tot = red2[0] + red2[1] + red2[2] + red2[3];
    float r = rsqrtf(tot / (float)D_H + 1e-8f);
#pragma unroll
    for (int w = 0; w < 2; ++w) {
        int d = tid + w * 256;
        h_out[(size_t)bt * D_H + d] = he[w] * r * swiglu_norm[e * D_H + d];
    }
}

// ---------------- generic fp32 GEMM: C[m,o] = epi(sum_k A[m,k]*W[o,k]) ----------------
// epi: 0 none, 1 silu, 2 sigmoid, 3 aux*acc, 4 silu(aux)*acc
#define GTILE 64
#define GBK 16
__global__ __launch_bounds__(256) void gemm_bt_kernel(
    const float* __restrict__ A, const float* __restrict__ W,
    const float* __restrict__ aux, float* __restrict__ C,
    int M, int O, int K, int epi)
{
    __shared__ float As[GBK][GTILE + 4];
    __shared__ float Ws[GBK][GTILE + 4];
    int tid = threadIdx.x;
    int tx = tid & 15, ty = tid >> 4;
    int bo = blockIdx.x * GTILE;
    int bm = blockIdx.y * GTILE;
    float acc[4][4] = {};
    int lrow = tid >> 2;
    int lcol = (tid & 3) * 4;
    for (int k0 = 0; k0 < K; k0 += GBK) {
        float4 av = make_float4(0, 0, 0, 0);
        if (k0 + lcol < K)  // K % 4 == 0, so a float4 is fully in or fully out
            av = *(const float4*)(A + (size_t)(bm + lrow) * K + k0 + lcol);
        As[lcol + 0][lrow] = av.x; As[lcol + 1][lrow] = av.y;
        As[lcol + 2][lrow] = av.z; As[lcol + 3][lrow] = av.w;
        float4 wv = make_float4(0, 0, 0, 0);
        int wrow = bo + lrow;
        if (wrow < O && k0 + lcol < K)
            wv = *(const float4*)(W + (size_t)wrow * K + k0 + lcol);
        Ws[lcol + 0][lrow] = wv.x; Ws[lcol + 1][lrow] = wv.y;
        Ws[lcol + 2][lrow] = wv.z; Ws[lcol + 3][lrow] = wv.w;
        __syncthreads();
#pragma unroll
        for (int kk = 0; kk < GBK; ++kk) {
            float4 a = *(const float4*)&As[kk][ty * 4];
            float4 bb = *(const float4*)&Ws[kk][tx * 4];
            float avv[4] = {a.x, a.y, a.z, a.w};
            float bvv[4] = {bb.x, bb.y, bb.z, bb.w};
#pragma unroll
            for (int i = 0; i < 4; ++i)
#pragma unroll
                for (int j = 0; j < 4; ++j) acc[i][j] += avv[i] * bvv[j];
        }
        __syncthreads();
    }
#pragma unroll
    for (int i = 0; i < 4; ++i) {
        int m = bm + ty * 4 + i;
#pragma unroll
        for (int j = 0; j < 4; ++j) {
            int o = bo + tx * 4 + j;
            if (o >= O) continue;
            float v = acc[i][j];
            float rr;
            if (epi == 0) rr = v;
            else if (epi == 1) rr = v * sigmoidf_(v);
            else if (epi == 2) rr = sigmoidf_(v);
            else if (epi == 3) rr = aux[(size_t)m * O + o] * v;
            else { float ax = aux[(size_t)m * O + o]; rr = ax * sigmoidf_(ax) * v; }
            C[(size_t)m * O + o] = rr;
        }
    }
}

// ---------------- combine: out += gate*(H_res@stream + H_post*out_e) ----------------
__global__ __launch_bounds__(256) void combine_kernel(
    const float* __restrict__ stream, const float* __restrict__ oute,
    const float* __restrict__ Hpost, const float* __restrict__ Hres,
    const float* __restrict__ gate_all, float* __restrict__ out, int k)
{
    int bt = blockIdx.x; int b = bt >> 10; int t = bt & 1023;
    float gate = gate_all[(size_t)bt * 16 + (k + 1)];
    if (gate == 0.f) return;
    __shared__ float hr[16], hp[4];
    if (threadIdx.x < 16) hr[threadIdx.x] = Hres[((size_t)k * BT_TOT + bt) * 16 + threadIdx.x];
    if (threadIdx.x < 4) hp[threadIdx.x] = Hpost[((size_t)k * BT_TOT + bt) * 4 + threadIdx.x];
    __syncthreads();
#pragma unroll
    for (int w = 0; w < 2; ++w) {
        int d = threadIdx.x + w * 256;
        float oe = oute[(size_t)bt * D_H + d];
        float s0 = stream[(((size_t)b * 4 + 0) * T_LEN + t) * D_H + d];
        float s1 = stream[(((size_t)b * 4 + 1) * T_LEN + t) * D_H + d];
        float s2 = stream[(((size_t)b * 4 + 2) * T_LEN + t) * D_H + d];
        float s3 = stream[(((size_t)b * 4 + 3) * T_LEN + t) * D_H + d];
#pragma unroll
        for (int i = 0; i < 4; ++i) {
            float v = hp[i] * oe + hr[i*4+0]*s0 + hr[i*4+1]*s1 + hr[i*4+2]*s2 + hr[i*4+3]*s3;
            out[(((size_t)b * 4 + i) * T_LEN + t) * D_H + d] += gate * v;
        }
    }
}

extern "C" void kernel_launch(void* const* d_in, const int* in_sizes, int n_in,
                              void* d_out, int out_size, void* d_ws, size_t ws_size,
                              hipStream_t stream) {
    const float* stream_in = (const float*)d_in[0];
    const float* norm_w    = (const float*)d_in[1];
    const float* phi_pre   = (const float*)d_in[2];
    const float* phi_post  = (const float*)d_in[3];
    const float* phi_res   = (const float*)d_in[4];
    const float* b_pre     = (const float*)d_in[5];
    const float* b_post    = (const float*)d_in[6];
    const float* b_res     = (const float*)d_in[7];
    const float* alpha_pre = (const float*)d_in[8];
    const float* alpha_post= (const float*)d_in[9];
    const float* alpha_res = (const float*)d_in[10];
    const float* sw_norm   = (const float*)d_in[11];
    const float* wd_w      = (const float*)d_in[12];
    const float* wu_w      = (const float*)d_in[13];
    const float* gate_w    = (const float*)d_in[14];
    const float* up_w      = (const float*)d_in[15];
    const float* down_w    = (const float*)d_in[16];
    const float* router_w  = (const float*)d_in[17];

    float* out = (float*)d_out;
    const int SU_N = 2 * 4 * T_LEN * D_H;           // 4,194,304
    float* gate_out = out + SU_N;                    // (B,T,16)
    float* lp_out = gate_out + BT_TOT * 16;          // (B,T)

    float* ws = (float*)d_ws;
    float* xn      = ws;                                  // BT*2048
    float* Hpost   = xn + (size_t)BT_TOT * ND;            // 15*BT*4
    float* Hres    = Hpost + (size_t)KEXP * BT_TOT * 4;   // 15*BT*16
    float* hbuf    = Hres + (size_t)KEXP * BT_TOT * 16;   // BT*512
    float* s1buf   = hbuf + (size_t)BT_TOT * D_H;         // BT*512
    float* gbuf    = s1buf + (size_t)BT_TOT * D_H;        // BT*512
    float* gatebuf = gbuf + (size_t)BT_TOT * D_H;         // BT*828
    float* tbuf    = gatebuf + (size_t)BT_TOT * DFFN;     // BT*828
    float* oute    = tbuf + (size_t)BT_TOT * DFFN;        // BT*512

    zero_kernel<<<(SU_N + 255) / 256, 256, 0, stream>>>(out, SU_N);
    router_kernel<<<BT_TOT, 64, 0, stream>>>(stream_in, router_w, gate_out, lp_out);
    xn_kernel<<<BT_TOT, 256, 0, stream>>>(stream_in, xn);

    for (int k = 0; k < KEXP; ++k) {
        int e = k + 1;
        mhc_kernel<<<BT_TOT, 256, 0, stream>>>(
            stream_in, xn, norm_w, phi_pre, phi_post, phi_res,
            b_pre, b_post, b_res, alpha_pre, alpha_post, alpha_res,
            sw_norm, hbuf, Hpost, Hres, k);
        // s1 = silu(h @ wd^T)
        gemm_bt_kernel<<<dim3(8, 32), 256, 0, stream>>>(
            hbuf, wd_w + (size_t)e * D_H * D_H, nullptr, s1buf, BT_TOT, D_H, D_H, 1);
        // g = sigmoid(s1 @ wu^T)
        gemm_bt_kernel<<<dim3(8, 32), 256, 0, stream>>>(
            s1buf, wu_w + (size_t)e * D_H * D_H, nullptr, gbuf, BT_TOT, D_H, D_H, 2);
        // gate_out = h @ gate^T
        gemm_bt_kernel<<<dim3(13, 32), 256, 0, stream>>>(
            hbuf, gate_w + (size_t)e * DFFN * D_H, nullptr, gatebuf, BT_TOT, DFFN, D_H, 0);
        // t = silu(gate_out) * (h @ up^T)
        gemm_bt_kernel<<<dim3(13, 32), 256, 0, stream>>>(
            hbuf, up_w + (size_t)e * DFFN * D_H, gatebuf, tbuf, BT_TOT, DFFN, D_H, 4);
        // out_e = g * (t @ down^T)
        gemm_bt_kernel<<<dim3(8, 32), 256, 0, stream>>>(
            tbuf, down_w + (size_t)e * D_H * DFFN, gbuf, oute, BT_TOT, D_H, DFFN, 3);
        combine_kernel<<<BT_TOT, 256, 0, stream>>>(
            stream_in, oute, Hpost, Hres, gate_out, out, k);
    }
}

// Round 2
// 956.302 us; speedup vs baseline: 4.7031x; 4.7031x over previous
//
#include <hip/hip_runtime.h>
#include <hip/hip_bf16.h>
#include <math.h>

typedef __attribute__((ext_vector_type(8))) short short8;
typedef __attribute__((ext_vector_type(4))) float floatx4;

#define T_LEN 1024
#define D_H 512
#define ND 2048
#define KEXP 15
#define DFFN 828
#define DFFN_P 896
#define BT_TOT 2048
#define PHI_ROWS 360
#define PHI_ROWS_P 384

// per-expert packed bf16 weight layout (elements)
#define WD_OFF   0
#define WU_OFF   262144
#define GATE_OFF 524288
#define UP_OFF   983040
#define DOWN_OFF 1441792
#define EXPW     1900544

__device__ __forceinline__ float sigmoidf_(float x) { return 1.f / (1.f + expf(-x)); }

// ---------------- zero fill ----------------
__global__ void zero_kernel(float* __restrict__ p, int n) {
    int i = blockIdx.x * blockDim.x + threadIdx.x;
    if (i < n) p[i] = 0.f;
}

// ---------------- router: gate_moe + route_lp ----------------
__global__ __launch_bounds__(64) void router_kernel(
    const float* __restrict__ stream, const float* __restrict__ rw,
    float* __restrict__ gate_out, float* __restrict__ lp_out)
{
    int bt = blockIdx.x; int b = bt >> 10; int t = bt & 1023;
    int lane = threadIdx.x;
    float ri[8];
#pragma unroll
    for (int w = 0; w < 8; ++w) {
        int d = lane + w * 64;
        float s = 0.f;
#pragma unroll
        for (int n = 0; n < 4; ++n)
            s += stream[(((size_t)b * 4 + n) * T_LEN + t) * D_H + d];
        ri[w] = 0.25f * s;
    }
    float logits[16];
    for (int e = 0; e < 16; ++e) {
        float p = 0.f;
#pragma unroll
        for (int w = 0; w < 8; ++w) p += ri[w] * rw[e * D_H + lane + w * 64];
#pragma unroll
        for (int off = 32; off; off >>= 1) p += __shfl_xor(p, off, 64);
        logits[e] = p;
    }
    float mx = logits[0];
    for (int e = 1; e < 16; ++e) mx = fmaxf(mx, logits[e]);
    float pr[16]; float sum = 0.f;
    for (int e = 0; e < 16; ++e) { pr[e] = expf(logits[e] - mx); sum += pr[e]; }
    float inv = 1.f / sum;
    for (int e = 0; e < 16; ++e) pr[e] *= inv;

    float gate[16]; bool taken[16];
    for (int e = 0; e < 16; ++e) { gate[e] = 0.f; taken[e] = false; }
    float prefix = 0.f;
    for (int rank = 0; rank < 4; ++rank) {
        int best = -1; float bp = -1.f;
        for (int e = 0; e < 16; ++e)
            if (!taken[e] && pr[e] > bp) { bp = pr[e]; best = e; }
        taken[best] = true;
        bool sel = (rank == 0) || (prefix < 0.8f);
        if (sel) gate[best] = bp;
        prefix += bp;
        if (!sel) break;
    }
    float lp = 0.f;
    for (int e = 0; e < 16; ++e)
        if (gate[e] > 0.f) lp += fmaxf(logf(pr[e]), -10.f);
    if (lane < 16) gate_out[(size_t)bt * 16 + lane] = gate[lane];
    if (lane == 0) lp_out[bt] = lp;
}

// ---------------- xn = rmsnorm(x) over nd=2048, bf16 out ----------------
__global__ __launch_bounds__(256) void xn_kernel(
    const float* __restrict__ stream, __hip_bfloat16* __restrict__ xn)
{
    int bt = blockIdx.x; int b = bt >> 10; int t = bt & 1023;
    int tid = threadIdx.x;
    float v[8]; float ss = 0.f;
#pragma unroll
    for (int w = 0; w < 8; ++w) {
        int j = tid + w * 256;
        int n = j >> 9, d = j & 511;
        float x = stream[(((size_t)b * 4 + n) * T_LEN + t) * D_H + d];
        v[w] = x; ss += x * x;
    }
#pragma unroll
    for (int off = 32; off; off >>= 1) ss += __shfl_down(ss, off, 64);
    __shared__ float red[4];
    int wave = tid >> 6, lane = tid & 63;
    if (lane == 0) red[wave] = ss;
    __syncthreads();
    float tot = red[0] + red[1] + red[2] + red[3];
    float r = rsqrtf(tot / (float)ND + 1e-8f);
#pragma unroll
    for (int w = 0; w < 8; ++w)
        xn[(size_t)bt * ND + tid + w * 256] = __float2bfloat16(v[w] * r);
}

// ---------------- phi_eff -> bf16 [384][2048], norm_w folded, rows>=360 zero ----------------
__global__ __launch_bounds__(256) void cvt_phi_kernel(
    const float* __restrict__ norm_w, const float* __restrict__ phi_pre,
    const float* __restrict__ phi_post, const float* __restrict__ phi_res,
    __hip_bfloat16* __restrict__ phi_all)
{
    int idx = blockIdx.x * 256 + threadIdx.x;   // < 384*2048
    int row = idx >> 11, col = idx & 2047;
    float v = 0.f;
    if (row < PHI_ROWS) {
        int k = row / 24, j = row - k * 24, e = k + 1;
        float nw = norm_w[(size_t)e * ND + col];
        float p;
        if (j < 4)      p = phi_pre[((size_t)e * 4 + j) * ND + col];
        else if (j < 8) p = phi_post[((size_t)e * 4 + (j - 4)) * ND + col];
        else            p = phi_res[((size_t)e * 16 + (j - 8)) * ND + col];
        v = p * nw;
    }
    phi_all[idx] = __float2bfloat16(v);
}

// ---------------- generic fp32->bf16 weight convert w/ zero padding ----------------
__global__ __launch_bounds__(256) void cvt_w_kernel(
    const float* __restrict__ src, __hip_bfloat16* __restrict__ dst,
    int srows, int scols, int dcols, int e0, size_t dstride)
{
    int z = blockIdx.y;
    int idx = blockIdx.x * 256 + threadIdx.x;   // < drows*dcols
    int r = idx / dcols, c = idx - r * dcols;
    float v = 0.f;
    if (r < srows && c < scols)
        v = src[(size_t)(e0 + z) * srows * scols + (size_t)r * scols + c];
    dst[(size_t)z * dstride + idx] = __float2bfloat16(v);
}

// ---------------- MFMA GEMM: C[m,o] = epi(sum_k A[m,k] * W[o,k]) ----------------
// epi: 0 f32, 1 silu bf16, 2 sigmoid bf16, 3 aux*acc bf16, 4 silu(aux)*acc bf16,
//      5 plain bf16, 6 atomicAdd f32 (split-K)
#define BM 128
#define BN 128
#define BK 32
#define LDSS 40
__global__ __launch_bounds__(256) void gemm_mfma(
    const __hip_bfloat16* __restrict__ A, const __hip_bfloat16* __restrict__ W,
    const __hip_bfloat16* __restrict__ aux, void* __restrict__ Cv,
    int Ka, int Oc, int kLen, int kzStride,
    size_t zA, size_t zW, size_t zC, int epi)
{
    __shared__ __align__(16) unsigned short As[BM * LDSS];
    __shared__ __align__(16) unsigned short Ws[BN * LDSS];
    int tid = threadIdx.x;
    int z = blockIdx.z;
    const __hip_bfloat16* Ag = A + (size_t)z * zA;
    const __hip_bfloat16* Wg = W + (size_t)z * zW;
    int bo = blockIdx.x * BN;
    int bm = blockIdx.y * BM;
    int wid = tid >> 6, lane = tid & 63;
    int quad = lane >> 4, lr = lane & 15;
    int wm = (wid & 1) * 64, wn = (wid >> 1) * 64;
    int srow = tid >> 2;             // 0..63
    int schk = (tid & 3) * 8;        // 0,8,16,24

    floatx4 acc[4][4];
#pragma unroll
    for (int i = 0; i < 4; ++i)
#pragma unroll
        for (int j = 0; j < 4; ++j) { floatx4 zv = {0.f, 0.f, 0.f, 0.f}; acc[i][j] = zv; }

    int kbeg = z * kzStride;
    for (int k0 = kbeg; k0 < kbeg + kLen; k0 += BK) {
        float4 a0 = *(const float4*)(Ag + (size_t)(bm + srow) * Ka + k0 + schk);
        float4 a1 = *(const float4*)(Ag + (size_t)(bm + srow + 64) * Ka + k0 + schk);
        float4 w0 = *(const float4*)(Wg + (size_t)(bo + srow) * Ka + k0 + schk);
        float4 w1 = *(const float4*)(Wg + (size_t)(bo + srow + 64) * Ka + k0 + schk);
        __syncthreads();
        *(float4*)&As[srow * LDSS + schk] = a0;
        *(float4*)&As[(srow + 64) * LDSS + schk] = a1;
        *(float4*)&Ws[srow * LDSS + schk] = w0;
        *(float4*)&Ws[(srow + 64) * LDSS + schk] = w1;
        __syncthreads();
        short8 af[4], bf[4];
#pragma unroll
        for (int mi = 0; mi < 4; ++mi)
            af[mi] = *(const short8*)&As[(wm + mi * 16 + lr) * LDSS + quad * 8];
#pragma unroll
        for (int ni = 0; ni < 4; ++ni)
            bf[ni] = *(const short8*)&Ws[(wn + ni * 16 + lr) * LDSS + quad * 8];
#pragma unroll
        for (int mi = 0; mi < 4; ++mi)
#pragma unroll
            for (int ni = 0; ni < 4; ++ni)
                acc[mi][ni] = __builtin_amdgcn_mfma_f32_16x16x32_bf16(
                    af[mi], bf[ni], acc[mi][ni], 0, 0, 0);
    }

    float* Cf = (float*)Cv;
    __hip_bfloat16* Cb = (__hip_bfloat16*)Cv;
    const __hip_bfloat16* auxp = aux + (size_t)z * zC;
    size_t cz = (size_t)z * zC;
#pragma unroll
    for (int mi = 0; mi < 4; ++mi) {
        int row0 = bm + wm + mi * 16 + quad * 4;
#pragma unroll
        for (int ni = 0; ni < 4; ++ni) {
            int col = bo + wn + ni * 16 + lr;
#pragma unroll
            for (int r = 0; r < 4; ++r) {
                float v = acc[mi][ni][r];
                size_t off = cz + (size_t)(row0 + r) * Oc + col;
                if (epi == 0)      Cf[off] = v;
                else if (epi == 1) Cb[off] = __float2bfloat16(v * sigmoidf_(v));
                else if (epi == 2) Cb[off] = __float2bfloat16(sigmoidf_(v));
                else if (epi == 3) {
                    float a = __bfloat162float(auxp[(size_t)(row0 + r) * Oc + col]);
                    Cb[off] = __float2bfloat16(a * v);
                } else if (epi == 4) {
                    float a = __bfloat162float(auxp[(size_t)(row0 + r) * Oc + col]);
                    Cb[off] = __float2bfloat16(a * sigmoidf_(a) * v);
                } else if (epi == 5) Cb[off] = __float2bfloat16(v);
                else atomicAdd(&Cf[off], v);
            }
        }
    }
}

// ---------------- sigmoid/sinkhorn per (expert, token) ----------------
__global__ __launch_bounds__(256) void mhc_post_kernel(
    const float* __restrict__ Cproj,
    const float* __restrict__ b_pre, const float* __restrict__ b_post,
    const float* __restrict__ b_res, const float* __restrict__ a_pre,
    const float* __restrict__ a_post, const float* __restrict__ a_res,
    float* __restrict__ Hpre, float* __restrict__ Hpost, float* __restrict__ Hres)
{
    int gid = blockIdx.x * 256 + threadIdx.x;   // < 15*2048
    int k = gid >> 11, bt = gid & 2047, e = k + 1;
    const float* s = Cproj + (size_t)bt * PHI_ROWS_P + k * 24;
    float ap = a_pre[e], aq = a_post[e], ar = a_res[e];
#pragma unroll
    for (int n = 0; n < 4; ++n)
        Hpre[((size_t)k * BT_TOT + bt) * 4 + n] = sigmoidf_(ap * s[n] + b_pre[e * 4 + n]);
#pragma unroll
    for (int n = 0; n < 4; ++n)
        Hpost[((size_t)k * BT_TOT + bt) * 4 + n] = 2.f * sigmoidf_(aq * s[4 + n] + b_post[e * 4 + n]);
    float M[16];
#pragma unroll
    for (int i = 0; i < 16; ++i) M[i] = expf(ar * s[8 + i] + b_res[e * 16 + i]);
#pragma unroll
    for (int it = 0; it < 6; ++it) {
#pragma unroll
        for (int i = 0; i < 4; ++i) {
            float iv = 1.f / (M[i*4] + M[i*4+1] + M[i*4+2] + M[i*4+3]);
            M[i*4] *= iv; M[i*4+1] *= iv; M[i*4+2] *= iv; M[i*4+3] *= iv;
        }
#pragma unroll
        for (int j = 0; j < 4; ++j) {
            float iv = 1.f / (M[j] + M[4+j] + M[8+j] + M[12+j]);
            M[j] *= iv; M[4+j] *= iv; M[8+j] *= iv; M[12+j] *= iv;
        }
    }
#pragma unroll
    for (int i = 0; i < 16; ++i) Hres[((size_t)k * BT_TOT + bt) * 16 + i] = M[i];
}

// ---------------- h = rmsnorm(H_pre @ stream) * swiglu_norm -> bf16 ----------------
__global__ __launch_bounds__(256) void h_kernel(
    const float* __restrict__ stream, const float* __restrict__ Hpre,
    const float* __restrict__ sw_norm, __hip_bfloat16* __restrict__ h, int k0g)
{
    int bt = blockIdx.x, z = blockIdx.y;
    int k = k0g + z, e = k + 1;
    int b = bt >> 10, t = bt & 1023;
    int tid = threadIdx.x;
    float hp[4];
#pragma unroll
    for (int n = 0; n < 4; ++n) hp[n] = Hpre[((size_t)k * BT_TOT + bt) * 4 + n];
    float he[2]; float ss = 0.f;
#pragma unroll
    for (int w = 0; w < 2; ++w) {
        int d = tid + w * 256;
        float v = 0.f;
#pragma unroll
        for (int n = 0; n < 4; ++n)
            v += hp[n] * stream[(((size_t)b * 4 + n) * T_LEN + t) * D_H + d];
        he[w] = v; ss += v * v;
    }
#pragma unroll
    for (int off = 32; off; off >>= 1) ss += __shfl_down(ss, off, 64);
    __shared__ float red[4];
    int wave = tid >> 6, lane = tid & 63;
    if (lane == 0) red[wave] = ss;
    __syncthreads();
    float tot = red[0] + red[1] + red[2] + red[3];
    float r = rsqrtf(tot / (float)D_H + 1e-8f);
#pragma unroll
    for (int w = 0; w < 2; ++w) {
        int d = tid + w * 256;
        h[((size_t)z * BT_TOT + bt) * D_H + d] =
            __float2bfloat16(he[w] * r * sw_norm[(size_t)e * D_H + d]);
    }
}

// ---------------- combine: out += sum_z gate*(H_res@stream + H_post*out_e) ----------------
__global__ __launch_bounds__(256) void combine_kernel(
    const float* __restrict__ stream, const __hip_bfloat16* __restrict__ oute,
    const float* __restrict__ Hpost, const float* __restrict__ Hres,
    const float* __restrict__ gate_all, float* __restrict__ out, int k0g, int G)
{
    int bt = blockIdx.x; int b = bt >> 10; int t = bt & 1023;
    int tid = threadIdx.x;
    float s[2][4], accv[2][4];
#pragma unroll
    for (int w = 0; w < 2; ++w) {
        int d = tid + w * 256;
#pragma unroll
        for (int n = 0; n < 4; ++n) {
            s[w][n] = stream[(((size_t)b * 4 + n) * T_LEN + t) * D_H + d];
            accv[w][n] = 0.f;
        }
    }
    for (int z = 0; z < G; ++z) {
        int k = k0g + z;
        float gate = gate_all[(size_t)bt * 16 + k + 1];
        if (gate == 0.f) continue;
        float hr[16], hp[4];
#pragma unroll
        for (int i = 0; i < 16; ++i) hr[i] = Hres[((size_t)k * BT_TOT + bt) * 16 + i];
#pragma unroll
        for (int i = 0; i < 4; ++i) hp[i] = Hpost[((size_t)k * BT_TOT + bt) * 4 + i];
#pragma unroll
        for (int w = 0; w < 2; ++w) {
            int d = tid + w * 256;
            float oe = __bfloat162float(oute[((size_t)z * BT_TOT + bt) * D_H + d]);
#pragma unroll
            for (int i = 0; i < 4; ++i) {
                float v = hp[i] * oe + hr[i*4+0]*s[w][0] + hr[i*4+1]*s[w][1]
                        + hr[i*4+2]*s[w][2] + hr[i*4+3]*s[w][3];
                accv[w][i] += gate * v;
            }
        }
    }
#pragma unroll
    for (int w = 0; w < 2; ++w) {
        int d = tid + w * 256;
#pragma unroll
        for (int i = 0; i < 4; ++i)
            out[(((size_t)b * 4 + i) * T_LEN + t) * D_H + d] += accv[w][i];
    }
}

extern "C" void kernel_launch(void* const* d_in, const int* in_sizes, int n_in,
                              void* d_out, int out_size, void* d_ws, size_t ws_size,
                              hipStream_t stream) {
    const float* stream_in = (const float*)d_in[0];
    const float* norm_w    = (const float*)d_in[1];
    const float* phi_pre   = (const float*)d_in[2];
    const float* phi_post  = (const float*)d_in[3];
    const float* phi_res   = (const float*)d_in[4];
    const float* b_pre     = (const float*)d_in[5];
    const float* b_post    = (const float*)d_in[6];
    const float* b_res     = (const float*)d_in[7];
    const float* alpha_pre = (const float*)d_in[8];
    const float* alpha_post= (const float*)d_in[9];
    const float* alpha_res = (const float*)d_in[10];
    const float* sw_norm   = (const float*)d_in[11];
    const float* wd_w      = (const float*)d_in[12];
    const float* wu_w      = (const float*)d_in[13];
    const float* gate_w    = (const float*)d_in[14];
    const float* up_w      = (const float*)d_in[15];
    const float* down_w    = (const float*)d_in[16];
    const float* router_w  = (const float*)d_in[17];

    float* out = (float*)d_out;
    const int SU_N = 2 * 4 * T_LEN * D_H;            // 4,194,304
    float* gate_out = out + SU_N;
    float* lp_out = gate_out + BT_TOT * 16;

    // ---- workspace carve-up ----
    char* p = (char*)d_ws;
    __hip_bfloat16* xn     = (__hip_bfloat16*)p; p += (size_t)BT_TOT * ND * 2;           // 8.39 MB
    __hip_bfloat16* phiall = (__hip_bfloat16*)p; p += (size_t)PHI_ROWS_P * ND * 2;       // 1.57 MB
    float* Cproj = (float*)p; p += (size_t)BT_TOT * PHI_ROWS_P * 4;                      // 3.15 MB
    float* Hpre  = (float*)p; p += (size_t)KEXP * BT_TOT * 4 * 4;
    float* Hpost = (float*)p; p += (size_t)KEXP * BT_TOT * 4 * 4;
    float* Hres  = (float*)p; p += (size_t)KEXP * BT_TOT * 16 * 4;
    size_t fixed_bytes = (size_t)(p - (char*)d_ws);
    size_t perE = (size_t)EXPW * 2                      // weights bf16
                + (size_t)BT_TOT * D_H * 2 * 4          // h, s1, g, oute (bf16)
                + (size_t)BT_TOT * DFFN_P * 2 * 2;      // gatebuf, t (bf16)
    int G = 1;
    if (fixed_bytes + 15 * perE <= ws_size) G = 15;
    else if (fixed_bytes + 5 * perE <= ws_size) G = 5;
    else if (fixed_bytes + 3 * perE <= ws_size) G = 3;

    __hip_bfloat16* wbuf = (__hip_bfloat16*)p; p += (size_t)G * EXPW * 2;
    __hip_bfloat16* hbuf = (__hip_bfloat16*)p; p += (size_t)G * BT_TOT * D_H * 2;
    __hip_bfloat16* s1b  = (__hip_bfloat16*)p; p += (size_t)G * BT_TOT * D_H * 2;
    __hip_bfloat16* gb   = (__hip_bfloat16*)p; p += (size_t)G * BT_TOT * D_H * 2;
    __hip_bfloat16* gateb= (__hip_bfloat16*)p; p += (size_t)G * BT_TOT * DFFN_P * 2;
    __hip_bfloat16* tb   = (__hip_bfloat16*)p; p += (size_t)G * BT_TOT * DFFN_P * 2;
    __hip_bfloat16* oute = (__hip_bfloat16*)p; p += (size_t)G * BT_TOT * D_H * 2;

    const size_t zD = (size_t)BT_TOT * D_H;      // 1M elements
    const size_t zF = (size_t)BT_TOT * DFFN_P;   // 1.83M elements

    // ---- fixed prologue ----
    zero_kernel<<<(SU_N + 255) / 256, 256, 0, stream>>>(out, SU_N);
    zero_kernel<<<(BT_TOT * PHI_ROWS_P + 255) / 256, 256, 0, stream>>>(Cproj, BT_TOT * PHI_ROWS_P);
    router_kernel<<<BT_TOT, 64, 0, stream>>>(stream_in, router_w, gate_out, lp_out);
    xn_kernel<<<BT_TOT, 256, 0, stream>>>(stream_in, xn);
    cvt_phi_kernel<<<(PHI_ROWS_P * ND) / 256, 256, 0, stream>>>(
        norm_w, phi_pre, phi_post, phi_res, phiall);
    // MHC projections: Cproj(2048x384) = xn(2048x2048) @ phiall^T, split-K=4 atomic
    gemm_mfma<<<dim3(3, 16, 4), 256, 0, stream>>>(
        xn, phiall, nullptr, Cproj, ND, PHI_ROWS_P, 512, 512, 0, 0, 0, 6);
    mhc_post_kernel<<<(KEXP * BT_TOT) / 256, 256, 0, stream>>>(
        Cproj, b_pre, b_post, b_res, alpha_pre, alpha_post, alpha_res, Hpre, Hpost, Hres);

    // ---- expert groups ----
    for (int kg = 0; kg < KEXP; kg += G) {
        int e0 = kg + 1;
        // weight conversions (zero-padded)
        cvt_w_kernel<<<dim3(262144 / 256, G), 256, 0, stream>>>(
            wd_w, wbuf + WD_OFF, 512, 512, 512, e0, EXPW);
        cvt_w_kernel<<<dim3(262144 / 256, G), 256, 0, stream>>>(
            wu_w, wbuf + WU_OFF, 512, 512, 512, e0, EXPW);
        cvt_w_kernel<<<dim3(458752 / 256, G), 256, 0, stream>>>(
            gate_w, wbuf + GATE_OFF, DFFN, 512, 512, e0, EXPW);
        cvt_w_kernel<<<dim3(458752 / 256, G), 256, 0, stream>>>(
            up_w, wbuf + UP_OFF, DFFN, 512, 512, e0, EXPW);
        cvt_w_kernel<<<dim3(458752 / 256, G), 256, 0, stream>>>(
            down_w, wbuf + DOWN_OFF, 512, DFFN, DFFN_P, e0, EXPW);

        h_kernel<<<dim3(BT_TOT, G), 256, 0, stream>>>(stream_in, Hpre, sw_norm, hbuf, kg);

        // s1 = silu(h @ wd^T)
        gemm_mfma<<<dim3(4, 16, G), 256, 0, stream>>>(
            hbuf, wbuf + WD_OFF, nullptr, s1b, 512, 512, 512, 0, zD, EXPW, zD, 1);
        // g = sigmoid(s1 @ wu^T)
        gemm_mfma<<<dim3(4, 16, G), 256, 0, stream>>>(
            s1b, wbuf + WU_OFF, nullptr, gb, 512, 512, 512, 0, zD, EXPW, zD, 2);
        // gatebuf = h @ gate^T
        gemm_mfma<<<dim3(7, 16, G), 256, 0, stream>>>(
            hbuf, wbuf + GATE_OFF, nullptr, gateb, 512, DFFN_P, 512, 0, zD, EXPW, zF, 5);
        // t = silu(gatebuf) * (h @ up^T)
        gemm_mfma<<<dim3(7, 16, G), 256, 0, stream>>>(
            hbuf, wbuf + UP_OFF, gateb, tb, 512, DFFN_P, 512, 0, zD, EXPW, zF, 4);
        // oute = g * (t @ down^T)
        gemm_mfma<<<dim3(4, 16, G), 256, 0, stream>>>(
            tb, wbuf + DOWN_OFF, gb, oute, DFFN_P, 512, DFFN_P, 0, zF, EXPW, zD, 3);

        combine_kernel<<<BT_TOT, 256, 0, stream>>>(
            stream_in, oute, Hpost, Hres, gate_out, out, kg, G);
    }
}

// Round 3
// 516.825 us; speedup vs baseline: 8.7023x; 1.8503x over previous
//
#include <hip/hip_runtime.h>
#include <hip/hip_bf16.h>
#include <math.h>

typedef __attribute__((ext_vector_type(8))) short short8;
typedef __attribute__((ext_vector_type(4))) float floatx4;

#define T_LEN 1024
#define D_H 512
#define ND 2048
#define KEXP 15
#define DFFN 828
#define DFFN_P 896
#define BT_TOT 2048
#define PHI_ROWS 360
#define PHI_ROWS_P 384
#define PAIR_CAP 8320   // 2048*4 max pairs + 128 pad rows

// per-expert packed bf16 weight layout (elements)
#define WD_OFF   0
#define WU_OFF   262144
#define GATE_OFF 524288
#define UP_OFF   983040
#define DOWN_OFF 1441792
#define EXPW     1900544

__device__ __forceinline__ float sigmoidf_(float x) { return 1.f / (1.f + expf(-x)); }

// ---------------- zero fill ----------------
__global__ void zero_kernel(float* __restrict__ p, int n) {
    int i = blockIdx.x * blockDim.x + threadIdx.x;
    if (i < n) p[i] = 0.f;
}

// ---------------- router: gate_moe + route_lp ----------------
__global__ __launch_bounds__(64) void router_kernel(
    const float* __restrict__ stream, const float* __restrict__ rw,
    float* __restrict__ gate_out, float* __restrict__ lp_out)
{
    int bt = blockIdx.x; int b = bt >> 10; int t = bt & 1023;
    int lane = threadIdx.x;
    float ri[8];
#pragma unroll
    for (int w = 0; w < 8; ++w) {
        int d = lane + w * 64;
        float s = 0.f;
#pragma unroll
        for (int n = 0; n < 4; ++n)
            s += stream[(((size_t)b * 4 + n) * T_LEN + t) * D_H + d];
        ri[w] = 0.25f * s;
    }
    float logits[16];
    for (int e = 0; e < 16; ++e) {
        float p = 0.f;
#pragma unroll
        for (int w = 0; w < 8; ++w) p += ri[w] * rw[e * D_H + lane + w * 64];
#pragma unroll
        for (int off = 32; off; off >>= 1) p += __shfl_xor(p, off, 64);
        logits[e] = p;
    }
    float mx = logits[0];
    for (int e = 1; e < 16; ++e) mx = fmaxf(mx, logits[e]);
    float pr[16]; float sum = 0.f;
    for (int e = 0; e < 16; ++e) { pr[e] = expf(logits[e] - mx); sum += pr[e]; }
    float inv = 1.f / sum;
    for (int e = 0; e < 16; ++e) pr[e] *= inv;

    float gate[16]; bool taken[16];
    for (int e = 0; e < 16; ++e) { gate[e] = 0.f; taken[e] = false; }
    float prefix = 0.f;
    for (int rank = 0; rank < 4; ++rank) {
        int best = -1; float bp = -1.f;
        for (int e = 0; e < 16; ++e)
            if (!taken[e] && pr[e] > bp) { bp = pr[e]; best = e; }
        taken[best] = true;
        bool sel = (rank == 0) || (prefix < 0.8f);
        if (sel) gate[best] = bp;
        prefix += bp;
        if (!sel) break;
    }
    float lp = 0.f;
    for (int e = 0; e < 16; ++e)
        if (gate[e] > 0.f) lp += fmaxf(logf(pr[e]), -10.f);
    if (lane < 16) gate_out[(size_t)bt * 16 + lane] = gate[lane];
    if (lane == 0) lp_out[bt] = lp;
}

// ---------------- build per-expert compacted token lists ----------------
__global__ __launch_bounds__(256) void build_lists_kernel(
    const float* __restrict__ gate_out, int* __restrict__ cnt,
    int* __restrict__ list, int* __restrict__ pos)
{
    int bt = blockIdx.x * 256 + threadIdx.x;
    if (bt >= BT_TOT) return;
    for (int k = 0; k < KEXP; ++k) {
        if (gate_out[(size_t)bt * 16 + k + 1] > 0.f) {
            int p = atomicAdd(&cnt[k], 1);
            list[k * BT_TOT + p] = bt;
            pos[k * BT_TOT + bt] = p;
        }
    }
}

__global__ void scan_kernel(const int* __restrict__ cnt, int* __restrict__ offs) {
    if (threadIdx.x == 0) {
        int a = 0;
        for (int k = 0; k < KEXP; ++k) { offs[k] = a; a += cnt[k]; }
        offs[KEXP] = a;
    }
}

// ---------------- xn = rmsnorm(x) over nd=2048, bf16 out ----------------
__global__ __launch_bounds__(256) void xn_kernel(
    const float* __restrict__ stream, __hip_bfloat16* __restrict__ xn)
{
    int bt = blockIdx.x; int b = bt >> 10; int t = bt & 1023;
    int tid = threadIdx.x;
    float v[8]; float ss = 0.f;
#pragma unroll
    for (int w = 0; w < 8; ++w) {
        int j = tid + w * 256;
        int n = j >> 9, d = j & 511;
        float x = stream[(((size_t)b * 4 + n) * T_LEN + t) * D_H + d];
        v[w] = x; ss += x * x;
    }
#pragma unroll
    for (int off = 32; off; off >>= 1) ss += __shfl_down(ss, off, 64);
    __shared__ float red[4];
    int wave = tid >> 6, lane = tid & 63;
    if (lane == 0) red[wave] = ss;
    __syncthreads();
    float tot = red[0] + red[1] + red[2] + red[3];
    float r = rsqrtf(tot / (float)ND + 1e-8f);
#pragma unroll
    for (int w = 0; w < 8; ++w)
        xn[(size_t)bt * ND + tid + w * 256] = __float2bfloat16(v[w] * r);
}

// ---------------- phi_eff -> bf16 [384][2048], norm_w folded ----------------
__global__ __launch_bounds__(256) void cvt_phi_kernel(
    const float* __restrict__ norm_w, const float* __restrict__ phi_pre,
    const float* __restrict__ phi_post, const float* __restrict__ phi_res,
    __hip_bfloat16* __restrict__ phi_all)
{
    int idx = blockIdx.x * 256 + threadIdx.x;
    int row = idx >> 11, col = idx & 2047;
    float v = 0.f;
    if (row < PHI_ROWS) {
        int k = row / 24, j = row - k * 24, e = k + 1;
        float nw = norm_w[(size_t)e * ND + col];
        float p;
        if (j < 4)      p = phi_pre[((size_t)e * 4 + j) * ND + col];
        else if (j < 8) p = phi_post[((size_t)e * 4 + (j - 4)) * ND + col];
        else            p = phi_res[((size_t)e * 16 + (j - 8)) * ND + col];
        v = p * nw;
    }
    phi_all[idx] = __float2bfloat16(v);
}

// ---------------- generic fp32->bf16 weight convert w/ zero padding ----------------
__global__ __launch_bounds__(256) void cvt_w_kernel(
    const float* __restrict__ src, __hip_bfloat16* __restrict__ dst,
    int srows, int scols, int dcols, int e0, size_t dstride)
{
    int z = blockIdx.y;
    int idx = blockIdx.x * 256 + threadIdx.x;
    int r = idx / dcols, c = idx - r * dcols;
    float v = 0.f;
    if (r < srows && c < scols)
        v = src[(size_t)(e0 + z) * srows * scols + (size_t)r * scols + c];
    dst[(size_t)z * dstride + idx] = __float2bfloat16(v);
}

// ---------------- MFMA GEMM (dense or compacted-arena) ----------------
// epi: 1 silu bf16, 2 sigmoid bf16, 3 aux*acc bf16, 6 atomicAdd f32 (split-K dense)
#define BM 128
#define BN 128
#define BK 32
#define LDSS 40
__global__ __launch_bounds__(256) void gemm_mfma(
    const __hip_bfloat16* __restrict__ A, const __hip_bfloat16* __restrict__ W,
    const __hip_bfloat16* __restrict__ aux, void* __restrict__ Cv,
    const int* __restrict__ counts, const int* __restrict__ offs, int kg,
    int Ka, int Oc, int kLen, int kzStride, size_t zW, int epi)
{
    __shared__ __align__(16) unsigned short As[BM * LDSS];
    __shared__ __align__(16) unsigned short Ws[BN * LDSS];
    int z = blockIdx.z;
    int bo = blockIdx.x * BN;
    int bm = blockIdx.y * BM;
    int base = 0, kbeg = 0;
    if (counts) {
        int k = kg + z;
        if (bm >= counts[k]) return;
        base = offs[k];
    } else {
        kbeg = z * kzStride;
    }
    const __hip_bfloat16* Ab = A + (size_t)base * Ka;
    const __hip_bfloat16* Wg = W + (size_t)z * zW;
    int tid = threadIdx.x;
    int wid = tid >> 6, lane = tid & 63;
    int quad = lane >> 4, lr = lane & 15;
    int wm = (wid & 1) * 64, wn = (wid >> 1) * 64;
    int srow = tid >> 2;
    int schk = (tid & 3) * 8;

    floatx4 acc[4][4];
#pragma unroll
    for (int i = 0; i < 4; ++i)
#pragma unroll
        for (int j = 0; j < 4; ++j) { floatx4 zv = {0.f, 0.f, 0.f, 0.f}; acc[i][j] = zv; }

    for (int k0 = kbeg; k0 < kbeg + kLen; k0 += BK) {
        float4 a0 = *(const float4*)(Ab + (size_t)(bm + srow) * Ka + k0 + schk);
        float4 a1 = *(const float4*)(Ab + (size_t)(bm + srow + 64) * Ka + k0 + schk);
        float4 w0 = *(const float4*)(Wg + (size_t)(bo + srow) * Ka + k0 + schk);
        float4 w1 = *(const float4*)(Wg + (size_t)(bo + srow + 64) * Ka + k0 + schk);
        __syncthreads();
        *(float4*)&As[srow * LDSS + schk] = a0;
        *(float4*)&As[(srow + 64) * LDSS + schk] = a1;
        *(float4*)&Ws[srow * LDSS + schk] = w0;
        *(float4*)&Ws[(srow + 64) * LDSS + schk] = w1;
        __syncthreads();
        short8 af[4], bf[4];
#pragma unroll
        for (int mi = 0; mi < 4; ++mi)
            af[mi] = *(const short8*)&As[(wm + mi * 16 + lr) * LDSS + quad * 8];
#pragma unroll
        for (int ni = 0; ni < 4; ++ni)
            bf[ni] = *(const short8*)&Ws[(wn + ni * 16 + lr) * LDSS + quad * 8];
#pragma unroll
        for (int mi = 0; mi < 4; ++mi)
#pragma unroll
            for (int ni = 0; ni < 4; ++ni)
                acc[mi][ni] = __builtin_amdgcn_mfma_f32_16x16x32_bf16(
                    af[mi], bf[ni], acc[mi][ni], 0, 0, 0);
    }

    float* Cf = (float*)Cv;
    __hip_bfloat16* Cb = (__hip_bfloat16*)Cv;
#pragma unroll
    for (int mi = 0; mi < 4; ++mi) {
        int row0 = bm + wm + mi * 16 + quad * 4;
#pragma unroll
        for (int ni = 0; ni < 4; ++ni) {
            int col = bo + wn + ni * 16 + lr;
#pragma unroll
            for (int r = 0; r < 4; ++r) {
                float v = acc[mi][ni][r];
                size_t off = (size_t)(base + row0 + r) * Oc + col;
                if (epi == 1)      Cb[off] = __float2bfloat16(v * sigmoidf_(v));
                else if (epi == 2) Cb[off] = __float2bfloat16(sigmoidf_(v));
                else if (epi == 3) {
                    float a = __bfloat162float(aux[off]);
                    Cb[off] = __float2bfloat16(a * v);
                } else atomicAdd(&Cf[off], v);
            }
        }
    }
}

// ---------------- fused gate+up GEMM: t = silu(h@Wg^T) * (h@Wu^T) ----------------
__global__ __launch_bounds__(256) void gemm2_mfma(
    const __hip_bfloat16* __restrict__ A, const __hip_bfloat16* __restrict__ Wgp,
    const __hip_bfloat16* __restrict__ Wup, __hip_bfloat16* __restrict__ Ct,
    const int* __restrict__ counts, const int* __restrict__ offs, int kg)
{
    __shared__ __align__(16) unsigned short As[BM * LDSS];
    __shared__ __align__(16) unsigned short Gs[BN * LDSS];
    __shared__ __align__(16) unsigned short Us[BN * LDSS];
    int z = blockIdx.z;
    int k = kg + z;
    int bo = blockIdx.x * BN;
    int bm = blockIdx.y * BM;
    if (bm >= counts[k]) return;
    int base = offs[k];
    const __hip_bfloat16* Ab = A + (size_t)base * D_H;
    const __hip_bfloat16* Wg = Wgp + (size_t)z * EXPW;
    const __hip_bfloat16* Wu = Wup + (size_t)z * EXPW;
    int tid = threadIdx.x;
    int wid = tid >> 6, lane = tid & 63;
    int quad = lane >> 4, lr = lane & 15;
    int wm = (wid & 1) * 64, wn = (wid >> 1) * 64;
    int srow = tid >> 2;
    int schk = (tid & 3) * 8;

    floatx4 ag[4][4], au[4][4];
#pragma unroll
    for (int i = 0; i < 4; ++i)
#pragma unroll
        for (int j = 0; j < 4; ++j) {
            floatx4 zv = {0.f, 0.f, 0.f, 0.f};
            ag[i][j] = zv; au[i][j] = zv;
        }

    for (int k0 = 0; k0 < D_H; k0 += BK) {
        float4 a0 = *(const float4*)(Ab + (size_t)(bm + srow) * D_H + k0 + schk);
        float4 a1 = *(const float4*)(Ab + (size_t)(bm + srow + 64) * D_H + k0 + schk);
        float4 g0 = *(const float4*)(Wg + (size_t)(bo + srow) * D_H + k0 + schk);
        float4 g1 = *(const float4*)(Wg + (size_t)(bo + srow + 64) * D_H + k0 + schk);
        float4 u0 = *(const float4*)(Wu + (size_t)(bo + srow) * D_H + k0 + schk);
        float4 u1 = *(const float4*)(Wu + (size_t)(bo + srow + 64) * D_H + k0 + schk);
        __syncthreads();
        *(float4*)&As[srow * LDSS + schk] = a0;
        *(float4*)&As[(srow + 64) * LDSS + schk] = a1;
        *(float4*)&Gs[srow * LDSS + schk] = g0;
        *(float4*)&Gs[(srow + 64) * LDSS + schk] = g1;
        *(float4*)&Us[srow * LDSS + schk] = u0;
        *(float4*)&Us[(srow + 64) * LDSS + schk] = u1;
        __syncthreads();
        short8 af[4], bg[4], bu[4];
#pragma unroll
        for (int mi = 0; mi < 4; ++mi)
            af[mi] = *(const short8*)&As[(wm + mi * 16 + lr) * LDSS + quad * 8];
#pragma unroll
        for (int ni = 0; ni < 4; ++ni) {
            bg[ni] = *(const short8*)&Gs[(wn + ni * 16 + lr) * LDSS + quad * 8];
            bu[ni] = *(const short8*)&Us[(wn + ni * 16 + lr) * LDSS + quad * 8];
        }
#pragma unroll
        for (int mi = 0; mi < 4; ++mi)
#pragma unroll
            for (int ni = 0; ni < 4; ++ni) {
                ag[mi][ni] = __builtin_amdgcn_mfma_f32_16x16x32_bf16(
                    af[mi], bg[ni], ag[mi][ni], 0, 0, 0);
                au[mi][ni] = __builtin_amdgcn_mfma_f32_16x16x32_bf16(
                    af[mi], bu[ni], au[mi][ni], 0, 0, 0);
            }
    }

#pragma unroll
    for (int mi = 0; mi < 4; ++mi) {
        int row0 = bm + wm + mi * 16 + quad * 4;
#pragma unroll
        for (int ni = 0; ni < 4; ++ni) {
            int col = bo + wn + ni * 16 + lr;
#pragma unroll
            for (int r = 0; r < 4; ++r) {
                float gg = ag[mi][ni][r];
                float uu = au[mi][ni][r];
                Ct[(size_t)(base + row0 + r) * DFFN_P + col] =
                    __float2bfloat16(gg * sigmoidf_(gg) * uu);
            }
        }
    }
}

// ---------------- sigmoid/sinkhorn per (expert, token) ----------------
__global__ __launch_bounds__(256) void mhc_post_kernel(
    const float* __restrict__ Cproj,
    const float* __restrict__ b_pre, const float* __restrict__ b_post,
    const float* __restrict__ b_res, const float* __restrict__ a_pre,
    const float* __restrict__ a_post, const float* __restrict__ a_res,
    float* __restrict__ Hpre, float* __restrict__ Hpost, float* __restrict__ Hres)
{
    int gid = blockIdx.x * 256 + threadIdx.x;
    int k = gid >> 11, bt = gid & 2047, e = k + 1;
    const float* s = Cproj + (size_t)bt * PHI_ROWS_P + k * 24;
    float ap = a_pre[e], aq = a_post[e], ar = a_res[e];
#pragma unroll
    for (int n = 0; n < 4; ++n)
        Hpre[((size_t)k * BT_TOT + bt) * 4 + n] = sigmoidf_(ap * s[n] + b_pre[e * 4 + n]);
#pragma unroll
    for (int n = 0; n < 4; ++n)
        Hpost[((size_t)k * BT_TOT + bt) * 4 + n] = 2.f * sigmoidf_(aq * s[4 + n] + b_post[e * 4 + n]);
    float M[16];
#pragma unroll
    for (int i = 0; i < 16; ++i) M[i] = expf(ar * s[8 + i] + b_res[e * 16 + i]);
#pragma unroll
    for (int it = 0; it < 6; ++it) {
#pragma unroll
        for (int i = 0; i < 4; ++i) {
            float iv = 1.f / (M[i*4] + M[i*4+1] + M[i*4+2] + M[i*4+3]);
            M[i*4] *= iv; M[i*4+1] *= iv; M[i*4+2] *= iv; M[i*4+3] *= iv;
        }
#pragma unroll
        for (int j = 0; j < 4; ++j) {
            float iv = 1.f / (M[j] + M[4+j] + M[8+j] + M[12+j]);
            M[j] *= iv; M[4+j] *= iv; M[8+j] *= iv; M[12+j] *= iv;
        }
    }
#pragma unroll
    for (int i = 0; i < 16; ++i) Hres[((size_t)k * BT_TOT + bt) * 16 + i] = M[i];
}

// ---------------- h (compacted) = rmsnorm(H_pre @ stream) * swiglu_norm ----------------
__global__ __launch_bounds__(256) void h_kernel(
    const float* __restrict__ stream, const float* __restrict__ Hpre,
    const float* __restrict__ sw_norm, const int* __restrict__ list,
    const int* __restrict__ counts, const int* __restrict__ offs,
    __hip_bfloat16* __restrict__ hA)
{
    int k = blockIdx.y;
    int i = blockIdx.x;
    if (i >= counts[k]) return;
    int bt = list[k * BT_TOT + i];
    int e = k + 1;
    int b = bt >> 10, t = bt & 1023;
    int tid = threadIdx.x;
    float hp[4];
#pragma unroll
    for (int n = 0; n < 4; ++n) hp[n] = Hpre[((size_t)k * BT_TOT + bt) * 4 + n];
    float he[2]; float ss = 0.f;
#pragma unroll
    for (int w = 0; w < 2; ++w) {
        int d = tid + w * 256;
        float v = 0.f;
#pragma unroll
        for (int n = 0; n < 4; ++n)
            v += hp[n] * stream[(((size_t)b * 4 + n) * T_LEN + t) * D_H + d];
        he[w] = v; ss += v * v;
    }
#pragma unroll
    for (int off = 32; off; off >>= 1) ss += __shfl_down(ss, off, 64);
    __shared__ float red[4];
    int wave = tid >> 6, lane = tid & 63;
    if (lane == 0) red[wave] = ss;
    __syncthreads();
    float tot = red[0] + red[1] + red[2] + red[3];
    float r = rsqrtf(tot / (float)D_H + 1e-8f);
    size_t row = (size_t)(offs[k] + i);
#pragma unroll
    for (int w = 0; w < 2; ++w) {
        int d = tid + w * 256;
        hA[row * D_H + d] = __float2bfloat16(he[w] * r * sw_norm[(size_t)e * D_H + d]);
    }
}

// ---------------- combine: out = sum_k gate*(H_res@stream + H_post*oute) ----------------
__global__ __launch_bounds__(256) void combine_kernel(
    const float* __restrict__ stream, const __hip_bfloat16* __restrict__ outeA,
    const float* __restrict__ Hpost, const float* __restrict__ Hres,
    const float* __restrict__ gate_all, const int* __restrict__ pos,
    const int* __restrict__ offs, float* __restrict__ out)
{
    int bt = blockIdx.x; int b = bt >> 10; int t = bt & 1023;
    int tid = threadIdx.x;
    float s[2][4], accv[2][4];
#pragma unroll
    for (int w = 0; w < 2; ++w) {
        int d = tid + w * 256;
#pragma unroll
        for (int n = 0; n < 4; ++n) {
            s[w][n] = stream[(((size_t)b * 4 + n) * T_LEN + t) * D_H + d];
            accv[w][n] = 0.f;
        }
    }
    for (int k = 0; k < KEXP; ++k) {
        float gate = gate_all[(size_t)bt * 16 + k + 1];
        if (gate == 0.f) continue;
        size_t row = (size_t)(offs[k] + pos[k * BT_TOT + bt]);
        float hr[16], hp[4];
#pragma unroll
        for (int i = 0; i < 16; ++i) hr[i] = Hres[((size_t)k * BT_TOT + bt) * 16 + i];
#pragma unroll
        for (int i = 0; i < 4; ++i) hp[i] = Hpost[((size_t)k * BT_TOT + bt) * 4 + i];
#pragma unroll
        for (int w = 0; w < 2; ++w) {
            int d = tid + w * 256;
            float oe = __bfloat162float(outeA[row * D_H + d]);
#pragma unroll
            for (int i = 0; i < 4; ++i) {
                float v = hp[i] * oe + hr[i*4+0]*s[w][0] + hr[i*4+1]*s[w][1]
                        + hr[i*4+2]*s[w][2] + hr[i*4+3]*s[w][3];
                accv[w][i] += gate * v;
            }
        }
    }
#pragma unroll
    for (int w = 0; w < 2; ++w) {
        int d = tid + w * 256;
#pragma unroll
        for (int i = 0; i < 4; ++i)
            out[(((size_t)b * 4 + i) * T_LEN + t) * D_H + d] = accv[w][i];
    }
}

extern "C" void kernel_launch(void* const* d_in, const int* in_sizes, int n_in,
                              void* d_out, int out_size, void* d_ws, size_t ws_size,
                              hipStream_t stream) {
    const float* stream_in = (const float*)d_in[0];
    const float* norm_w    = (const float*)d_in[1];
    const float* phi_pre   = (const float*)d_in[2];
    const float* phi_post  = (const float*)d_in[3];
    const float* phi_res   = (const float*)d_in[4];
    const float* b_pre     = (const float*)d_in[5];
    const float* b_post    = (const float*)d_in[6];
    const float* b_res     = (const float*)d_in[7];
    const float* alpha_pre = (const float*)d_in[8];
    const float* alpha_post= (const float*)d_in[9];
    const float* alpha_res = (const float*)d_in[10];
    const float* sw_norm   = (const float*)d_in[11];
    const float* wd_w      = (const float*)d_in[12];
    const float* wu_w      = (const float*)d_in[13];
    const float* gate_w    = (const float*)d_in[14];
    const float* up_w      = (const float*)d_in[15];
    const float* down_w    = (const float*)d_in[16];
    const float* router_w  = (const float*)d_in[17];

    float* out = (float*)d_out;
    const int SU_N = 2 * 4 * T_LEN * D_H;
    float* gate_out = out + SU_N;
    float* lp_out = gate_out + BT_TOT * 16;

    // ---- workspace carve-up ----
    char* p = (char*)d_ws;
    __hip_bfloat16* xn     = (__hip_bfloat16*)p; p += (size_t)BT_TOT * ND * 2;
    __hip_bfloat16* phiall = (__hip_bfloat16*)p; p += (size_t)PHI_ROWS_P * ND * 2;
    float* Cproj = (float*)p; p += (size_t)BT_TOT * PHI_ROWS_P * 4;
    float* Hpre  = (float*)p; p += (size_t)KEXP * BT_TOT * 4 * 4;
    float* Hpost = (float*)p; p += (size_t)KEXP * BT_TOT * 4 * 4;
    float* Hres  = (float*)p; p += (size_t)KEXP * BT_TOT * 16 * 4;
    int* cnt  = (int*)p; p += 256;
    int* offs = (int*)p; p += 256;
    int* list = (int*)p; p += (size_t)KEXP * BT_TOT * 4;
    int* pos  = (int*)p; p += (size_t)KEXP * BT_TOT * 4;
    __hip_bfloat16* hA    = (__hip_bfloat16*)p; p += (size_t)PAIR_CAP * D_H * 2;
    __hip_bfloat16* s1A   = (__hip_bfloat16*)p; p += (size_t)PAIR_CAP * D_H * 2;
    __hip_bfloat16* gA    = (__hip_bfloat16*)p; p += (size_t)PAIR_CAP * D_H * 2;
    __hip_bfloat16* outeA = (__hip_bfloat16*)p; p += (size_t)PAIR_CAP * D_H * 2;
    __hip_bfloat16* tA    = (__hip_bfloat16*)p; p += (size_t)PAIR_CAP * DFFN_P * 2;
    size_t fixed_bytes = (size_t)(p - (char*)d_ws);
    size_t perW = (size_t)EXPW * 2;
    size_t avail = ws_size > fixed_bytes ? ws_size - fixed_bytes : 0;
    int G = (int)(avail / perW);
    if (G > KEXP) G = KEXP;
    if (G < 1) G = 1;
    __hip_bfloat16* wbuf = (__hip_bfloat16*)p;

    // ---- prologue ----
    zero_kernel<<<1, 64, 0, stream>>>((float*)cnt, 16);
    zero_kernel<<<(BT_TOT * PHI_ROWS_P + 255) / 256, 256, 0, stream>>>(Cproj, BT_TOT * PHI_ROWS_P);
    router_kernel<<<BT_TOT, 64, 0, stream>>>(stream_in, router_w, gate_out, lp_out);
    build_lists_kernel<<<BT_TOT / 256, 256, 0, stream>>>(gate_out, cnt, list, pos);
    scan_kernel<<<1, 64, 0, stream>>>(cnt, offs);
    xn_kernel<<<BT_TOT, 256, 0, stream>>>(stream_in, xn);
    cvt_phi_kernel<<<(PHI_ROWS_P * ND) / 256, 256, 0, stream>>>(
        norm_w, phi_pre, phi_post, phi_res, phiall);
    // MHC projections: Cproj(2048x384) = xn @ phiall^T, split-K=4 atomic
    gemm_mfma<<<dim3(3, 16, 4), 256, 0, stream>>>(
        xn, phiall, nullptr, Cproj, nullptr, nullptr, 0, ND, PHI_ROWS_P, 512, 512, 0, 6);
    mhc_post_kernel<<<(KEXP * BT_TOT) / 256, 256, 0, stream>>>(
        Cproj, b_pre, b_post, b_res, alpha_pre, alpha_post, alpha_res, Hpre, Hpost, Hres);
    h_kernel<<<dim3(BT_TOT, KEXP), 256, 0, stream>>>(
        stream_in, Hpre, sw_norm, list, cnt, offs, hA);

    // ---- expert weight groups ----
    for (int kg = 0; kg < KEXP; kg += G) {
        int Gc = (kg + G <= KEXP) ? G : (KEXP - kg);
        int e0 = kg + 1;
        cvt_w_kernel<<<dim3(262144 / 256, Gc), 256, 0, stream>>>(
            wd_w, wbuf + WD_OFF, 512, 512, 512, e0, EXPW);
        cvt_w_kernel<<<dim3(262144 / 256, Gc), 256, 0, stream>>>(
            wu_w, wbuf + WU_OFF, 512, 512, 512, e0, EXPW);
        cvt_w_kernel<<<dim3(458752 / 256, Gc), 256, 0, stream>>>(
            gate_w, wbuf + GATE_OFF, DFFN, 512, 512, e0, EXPW);
        cvt_w_kernel<<<dim3(458752 / 256, Gc), 256, 0, stream>>>(
            up_w, wbuf + UP_OFF, DFFN, 512, 512, e0, EXPW);
        cvt_w_kernel<<<dim3(458752 / 256, Gc), 256, 0, stream>>>(
            down_w, wbuf + DOWN_OFF, 512, DFFN, DFFN_P, e0, EXPW);

        // s1 = silu(h @ wd^T)
        gemm_mfma<<<dim3(4, 16, Gc), 256, 0, stream>>>(
            hA, wbuf + WD_OFF, nullptr, s1A, cnt, offs, kg, 512, 512, 512, 0, EXPW, 1);
        // g = sigmoid(s1 @ wu^T)
        gemm_mfma<<<dim3(4, 16, Gc), 256, 0, stream>>>(
            s1A, wbuf + WU_OFF, nullptr, gA, cnt, offs, kg, 512, 512, 512, 0, EXPW, 2);
        // t = silu(h @ gate^T) * (h @ up^T)   [fused]
        gemm2_mfma<<<dim3(7, 16, Gc), 256, 0, stream>>>(
            hA, wbuf + GATE_OFF, wbuf + UP_OFF, tA, cnt, offs, kg);
        // oute = g * (t @ down^T)
        gemm_mfma<<<dim3(4, 16, Gc), 256, 0, stream>>>(
            tA, wbuf + DOWN_OFF, gA, outeA, cnt, offs, kg, DFFN_P, 512, DFFN_P, 0, EXPW, 3);
    }

    combine_kernel<<<BT_TOT, 256, 0, stream>>>(
        stream_in, outeA, Hpost, Hres, gate_out, pos, offs, out);
}

// Round 4
// 460.448 us; speedup vs baseline: 9.7678x; 1.1224x over previous
//
#include <hip/hip_runtime.h>
#include <hip/hip_bf16.h>
#include <math.h>

typedef __attribute__((ext_vector_type(8))) short short8;
typedef __attribute__((ext_vector_type(4))) float floatx4;

#define T_LEN 1024
#define D_H 512
#define ND 2048
#define KEXP 15
#define DFFN 828
#define DFFN_P 896
#define BT_TOT 2048
#define PHI_ROWS 360
#define PHI_ROWS_P 384
#define PAIR_CAP 8320

// per-expert packed bf16 weight layout (elements)
#define WD_OFF   0
#define WU_OFF   262144
#define GATE_OFF 524288
#define UP_OFF   983040
#define DOWN_OFF 1441792
#define EXPW     1900544

__device__ __forceinline__ float sigmoidf_(float x) { return 1.f / (1.f + expf(-x)); }
__device__ __forceinline__ unsigned short bf16b_(float x) {
    __hip_bfloat16 h = __float2bfloat16(x);
    return *reinterpret_cast<unsigned short*>(&h);
}

// ---------------- router + list build ----------------
__global__ __launch_bounds__(64) void router_kernel(
    const float* __restrict__ stream, const float* __restrict__ rw,
    float* __restrict__ gate_out, float* __restrict__ lp_out,
    int* __restrict__ cnt, int* __restrict__ list, int* __restrict__ pos)
{
    int bt = blockIdx.x; int b = bt >> 10; int t = bt & 1023;
    int lane = threadIdx.x;
    float ri[8];
#pragma unroll
    for (int w = 0; w < 8; ++w) {
        int d = lane + w * 64;
        float s = 0.f;
#pragma unroll
        for (int n = 0; n < 4; ++n)
            s += stream[(((size_t)b * 4 + n) * T_LEN + t) * D_H + d];
        ri[w] = 0.25f * s;
    }
    float logits[16];
    for (int e = 0; e < 16; ++e) {
        float p = 0.f;
#pragma unroll
        for (int w = 0; w < 8; ++w) p += ri[w] * rw[e * D_H + lane + w * 64];
#pragma unroll
        for (int off = 32; off; off >>= 1) p += __shfl_xor(p, off, 64);
        logits[e] = p;
    }
    float mx = logits[0];
    for (int e = 1; e < 16; ++e) mx = fmaxf(mx, logits[e]);
    float pr[16]; float sum = 0.f;
    for (int e = 0; e < 16; ++e) { pr[e] = expf(logits[e] - mx); sum += pr[e]; }
    float inv = 1.f / sum;
    for (int e = 0; e < 16; ++e) pr[e] *= inv;

    float gate[16]; bool taken[16];
    for (int e = 0; e < 16; ++e) { gate[e] = 0.f; taken[e] = false; }
    float prefix = 0.f;
    for (int rank = 0; rank < 4; ++rank) {
        int best = -1; float bp = -1.f;
        for (int e = 0; e < 16; ++e)
            if (!taken[e] && pr[e] > bp) { bp = pr[e]; best = e; }
        taken[best] = true;
        bool sel = (rank == 0) || (prefix < 0.8f);
        if (sel) gate[best] = bp;
        prefix += bp;
        if (!sel) break;
    }
    float lp = 0.f;
    for (int e = 0; e < 16; ++e)
        if (gate[e] > 0.f) lp += fmaxf(logf(pr[e]), -10.f);
    if (lane < 16) gate_out[(size_t)bt * 16 + lane] = gate[lane];
    if (lane == 0) lp_out[bt] = lp;
    // list build: lane e (1..15) handles expert e
    if (lane >= 1 && lane < 16 && gate[lane] > 0.f) {
        int k = lane - 1;
        int p = atomicAdd(&cnt[k], 1);
        list[k * BT_TOT + p] = bt;
        pos[k * BT_TOT + bt] = p;
    }
}

__global__ void scan_kernel(const int* __restrict__ cnt, int* __restrict__ offs) {
    if (threadIdx.x == 0) {
        int a = 0;
        for (int k = 0; k < KEXP; ++k) { offs[k] = a; a += cnt[k]; }
        offs[KEXP] = a;
    }
}

// ---------------- xn = rmsnorm(x) over nd=2048, bf16 out ----------------
__global__ __launch_bounds__(256) void xn_kernel(
    const float* __restrict__ stream, __hip_bfloat16* __restrict__ xn)
{
    int bt = blockIdx.x; int b = bt >> 10; int t = bt & 1023;
    int tid = threadIdx.x;
    float v[8]; float ss = 0.f;
#pragma unroll
    for (int w = 0; w < 8; ++w) {
        int j = tid + w * 256;
        int n = j >> 9, d = j & 511;
        float x = stream[(((size_t)b * 4 + n) * T_LEN + t) * D_H + d];
        v[w] = x; ss += x * x;
    }
#pragma unroll
    for (int off = 32; off; off >>= 1) ss += __shfl_down(ss, off, 64);
    __shared__ float red[4];
    int wave = tid >> 6, lane = tid & 63;
    if (lane == 0) red[wave] = ss;
    __syncthreads();
    float tot = red[0] + red[1] + red[2] + red[3];
    float r = rsqrtf(tot / (float)ND + 1e-8f);
#pragma unroll
    for (int w = 0; w < 8; ++w)
        xn[(size_t)bt * ND + tid + w * 256] = __float2bfloat16(v[w] * r);
}

// ---------------- phi_eff -> bf16 [384][2048], norm_w folded ----------------
__global__ __launch_bounds__(256) void cvt_phi_kernel(
    const float* __restrict__ norm_w, const float* __restrict__ phi_pre,
    const float* __restrict__ phi_post, const float* __restrict__ phi_res,
    __hip_bfloat16* __restrict__ phi_all)
{
    int idx = blockIdx.x * 256 + threadIdx.x;
    int row = idx >> 11, col = idx & 2047;
    float v = 0.f;
    if (row < PHI_ROWS) {
        int k = row / 24, j = row - k * 24, e = k + 1;
        float nw = norm_w[(size_t)e * ND + col];
        float p;
        if (j < 4)      p = phi_pre[((size_t)e * 4 + j) * ND + col];
        else if (j < 8) p = phi_post[((size_t)e * 4 + (j - 4)) * ND + col];
        else            p = phi_res[((size_t)e * 16 + (j - 8)) * ND + col];
        v = p * nw;
    }
    phi_all[idx] = __float2bfloat16(v);
}

// ---------------- single fused weight convert (all 5 types) ----------------
// type: 0 wd, 1 wu, 2 gate, 3 up, 4 down. 4-elem groups, float4 -> 4 bf16.
__global__ __launch_bounds__(256) void cvt_all_kernel(
    const float* __restrict__ wd, const float* __restrict__ wu,
    const float* __restrict__ gate, const float* __restrict__ up,
    const float* __restrict__ down, __hip_bfloat16* __restrict__ wbuf, int e0)
{
    int z = blockIdx.z;
    int type = blockIdx.y;
    int g = blockIdx.x * 256 + threadIdx.x;
    int e = e0 + z;
    __hip_bfloat16* dstb = wbuf + (size_t)z * EXPW;
    float4 v = make_float4(0.f, 0.f, 0.f, 0.f);
    size_t didx;
    if (type <= 1) {
        if (g >= 65536) return;
        didx = (type == 0 ? WD_OFF : WU_OFF) + (size_t)g * 4;
        const float* src = (type == 0 ? wd : wu) + (size_t)e * 262144;
        v = *(const float4*)(src + (size_t)g * 4);
    } else if (type <= 3) {
        if (g >= 114688) return;                       // dst 896x512
        size_t idx4 = (size_t)g * 4;
        didx = (type == 2 ? GATE_OFF : UP_OFF) + idx4;
        if (idx4 < (size_t)DFFN * 512) {               // rows-only padding: flat copy
            const float* src = (type == 2 ? gate : up) + (size_t)e * DFFN * 512;
            v = *(const float4*)(src + idx4);
        }
    } else {
        if (g >= 114688) return;                       // dst 512x896, src 512x828
        int r = g / 224, gc = g - r * 224;
        didx = DOWN_OFF + (size_t)g * 4;
        if (gc < 207)
            v = *(const float4*)(down + (size_t)e * 512 * DFFN + (size_t)r * DFFN + gc * 4);
    }
    ushort4 o;
    o.x = bf16b_(v.x); o.y = bf16b_(v.y); o.z = bf16b_(v.z); o.w = bf16b_(v.w);
    *(ushort4*)((unsigned short*)dstb + didx) = o;
}

// ---------------- dense 128x128 MFMA GEMM (phi projections, split-K atomic) ----------------
#define BM 128
#define BN 128
#define BK 32
#define LDSS 40
__global__ __launch_bounds__(256) void gemm_mfma(
    const __hip_bfloat16* __restrict__ A, const __hip_bfloat16* __restrict__ W,
    float* __restrict__ Cf, int Ka, int Oc, int kLen, int kzStride)
{
    __shared__ __align__(16) unsigned short As[BM * LDSS];
    __shared__ __align__(16) unsigned short Ws[BN * LDSS];
    int z = blockIdx.z;
    int bo = blockIdx.x * BN;
    int bm = blockIdx.y * BM;
    int kbeg = z * kzStride;
    int tid = threadIdx.x;
    int wid = tid >> 6, lane = tid & 63;
    int quad = lane >> 4, lr = lane & 15;
    int wm = (wid & 1) * 64, wn = (wid >> 1) * 64;
    int srow = tid >> 2;
    int schk = (tid & 3) * 8;

    floatx4 acc[4][4];
#pragma unroll
    for (int i = 0; i < 4; ++i)
#pragma unroll
        for (int j = 0; j < 4; ++j) { floatx4 zv = {0.f, 0.f, 0.f, 0.f}; acc[i][j] = zv; }

    for (int k0 = kbeg; k0 < kbeg + kLen; k0 += BK) {
        float4 a0 = *(const float4*)(A + (size_t)(bm + srow) * Ka + k0 + schk);
        float4 a1 = *(const float4*)(A + (size_t)(bm + srow + 64) * Ka + k0 + schk);
        float4 w0 = *(const float4*)(W + (size_t)(bo + srow) * Ka + k0 + schk);
        float4 w1 = *(const float4*)(W + (size_t)(bo + srow + 64) * Ka + k0 + schk);
        __syncthreads();
        *(float4*)&As[srow * LDSS + schk] = a0;
        *(float4*)&As[(srow + 64) * LDSS + schk] = a1;
        *(float4*)&Ws[srow * LDSS + schk] = w0;
        *(float4*)&Ws[(srow + 64) * LDSS + schk] = w1;
        __syncthreads();
        short8 af[4], bf[4];
#pragma unroll
        for (int mi = 0; mi < 4; ++mi)
            af[mi] = *(const short8*)&As[(wm + mi * 16 + lr) * LDSS + quad * 8];
#pragma unroll
        for (int ni = 0; ni < 4; ++ni)
            bf[ni] = *(const short8*)&Ws[(wn + ni * 16 + lr) * LDSS + quad * 8];
#pragma unroll
        for (int mi = 0; mi < 4; ++mi)
#pragma unroll
            for (int ni = 0; ni < 4; ++ni)
                acc[mi][ni] = __builtin_amdgcn_mfma_f32_16x16x32_bf16(
                    af[mi], bf[ni], acc[mi][ni], 0, 0, 0);
    }
#pragma unroll
    for (int mi = 0; mi < 4; ++mi) {
        int row0 = bm + wm + mi * 16 + quad * 4;
#pragma unroll
        for (int ni = 0; ni < 4; ++ni) {
            int col = bo + wn + ni * 16 + lr;
#pragma unroll
            for (int r = 0; r < 4; ++r)
                atomicAdd(&Cf[(size_t)(row0 + r) * Oc + col], acc[mi][ni][r]);
        }
    }
}

// ---------------- fused s1 + gate/up GEMM (arena) ----------------
// blockIdx.x < 4: s1 = silu(h @ wd^T), N=512 -> s1A
// blockIdx.x >= 4: t = silu(h @ gate^T) * (h @ up^T), N=896 -> tA
__global__ __launch_bounds__(256) void gemm_fused(
    const __hip_bfloat16* __restrict__ A, const __hip_bfloat16* __restrict__ wbuf,
    __hip_bfloat16* __restrict__ s1A, __hip_bfloat16* __restrict__ tA,
    const int* __restrict__ counts, const int* __restrict__ offs, int kg)
{
    __shared__ __align__(16) unsigned short As[BM * LDSS];
    __shared__ __align__(16) unsigned short Gs[BN * LDSS];
    __shared__ __align__(16) unsigned short Us[BN * LDSS];
    int z = blockIdx.z;
    int k = kg + z;
    int bm = blockIdx.y * BM;
    if (bm >= counts[k]) return;
    int base = offs[k];
    bool dual = (blockIdx.x >= 4);
    int bo = dual ? (blockIdx.x - 4) * BN : blockIdx.x * BN;
    const __hip_bfloat16* Ab = A + (size_t)base * D_H;
    const __hip_bfloat16* W1 = wbuf + (size_t)z * EXPW + (dual ? GATE_OFF : WD_OFF);
    const __hip_bfloat16* W2 = wbuf + (size_t)z * EXPW + UP_OFF;
    int tid = threadIdx.x;
    int wid = tid >> 6, lane = tid & 63;
    int quad = lane >> 4, lr = lane & 15;
    int wm = (wid & 1) * 64, wn = (wid >> 1) * 64;
    int srow = tid >> 2;
    int schk = (tid & 3) * 8;

    floatx4 a1[4][4], a2[4][4];
#pragma unroll
    for (int i = 0; i < 4; ++i)
#pragma unroll
        for (int j = 0; j < 4; ++j) {
            floatx4 zv = {0.f, 0.f, 0.f, 0.f};
            a1[i][j] = zv; a2[i][j] = zv;
        }

    for (int k0 = 0; k0 < D_H; k0 += BK) {
        float4 x0 = *(const float4*)(Ab + (size_t)(bm + srow) * D_H + k0 + schk);
        float4 x1 = *(const float4*)(Ab + (size_t)(bm + srow + 64) * D_H + k0 + schk);
        float4 g0 = *(const float4*)(W1 + (size_t)(bo + srow) * D_H + k0 + schk);
        float4 g1 = *(const float4*)(W1 + (size_t)(bo + srow + 64) * D_H + k0 + schk);
        float4 u0, u1;
        if (dual) {
            u0 = *(const float4*)(W2 + (size_t)(bo + srow) * D_H + k0 + schk);
            u1 = *(const float4*)(W2 + (size_t)(bo + srow + 64) * D_H + k0 + schk);
        }
        __syncthreads();
        *(float4*)&As[srow * LDSS + schk] = x0;
        *(float4*)&As[(srow + 64) * LDSS + schk] = x1;
        *(float4*)&Gs[srow * LDSS + schk] = g0;
        *(float4*)&Gs[(srow + 64) * LDSS + schk] = g1;
        if (dual) {
            *(float4*)&Us[srow * LDSS + schk] = u0;
            *(float4*)&Us[(srow + 64) * LDSS + schk] = u1;
        }
        __syncthreads();
        short8 af[4], bg[4];
#pragma unroll
        for (int mi = 0; mi < 4; ++mi)
            af[mi] = *(const short8*)&As[(wm + mi * 16 + lr) * LDSS + quad * 8];
#pragma unroll
        for (int ni = 0; ni < 4; ++ni)
            bg[ni] = *(const short8*)&Gs[(wn + ni * 16 + lr) * LDSS + quad * 8];
#pragma unroll
        for (int mi = 0; mi < 4; ++mi)
#pragma unroll
            for (int ni = 0; ni < 4; ++ni)
                a1[mi][ni] = __builtin_amdgcn_mfma_f32_16x16x32_bf16(
                    af[mi], bg[ni], a1[mi][ni], 0, 0, 0);
        if (dual) {
            short8 bu[4];
#pragma unroll
            for (int ni = 0; ni < 4; ++ni)
                bu[ni] = *(const short8*)&Us[(wn + ni * 16 + lr) * LDSS + quad * 8];
#pragma unroll
            for (int mi = 0; mi < 4; ++mi)
#pragma unroll
                for (int ni = 0; ni < 4; ++ni)
                    a2[mi][ni] = __builtin_amdgcn_mfma_f32_16x16x32_bf16(
                        af[mi], bu[ni], a2[mi][ni], 0, 0, 0);
        }
    }

#pragma unroll
    for (int mi = 0; mi < 4; ++mi) {
        int row0 = bm + wm + mi * 16 + quad * 4;
#pragma unroll
        for (int ni = 0; ni < 4; ++ni) {
            int col = bo + wn + ni * 16 + lr;
#pragma unroll
            for (int r = 0; r < 4; ++r) {
                float v = a1[mi][ni][r];
                if (dual) {
                    float uu = a2[mi][ni][r];
                    tA[(size_t)(base + row0 + r) * DFFN_P + col] =
                        __float2bfloat16(v * sigmoidf_(v) * uu);
                } else {
                    s1A[(size_t)(base + row0 + r) * D_H + col] =
                        __float2bfloat16(v * sigmoidf_(v));
                }
            }
        }
    }
}

// ---------------- 64x128 MFMA GEMM (arena), epi 2 sigmoid / 3 aux*acc ----------------
#define BM64 64
__global__ __launch_bounds__(256) void gemm_mfma64(
    const __hip_bfloat16* __restrict__ A, const __hip_bfloat16* __restrict__ W,
    const __hip_bfloat16* __restrict__ aux, __hip_bfloat16* __restrict__ C,
    const int* __restrict__ counts, const int* __restrict__ offs, int kg,
    int Ka, int Oc, size_t woff, int epi)
{
    __shared__ __align__(16) unsigned short As[BM64 * LDSS];
    __shared__ __align__(16) unsigned short Ws[BN * LDSS];
    int z = blockIdx.z;
    int k = kg + z;
    int bm = blockIdx.y * BM64;
    if (bm >= counts[k]) return;
    int base = offs[k];
    int bo = blockIdx.x * BN;
    const __hip_bfloat16* Ab = A + (size_t)base * Ka;
    const __hip_bfloat16* Wg = W + (size_t)z * EXPW + woff;
    int tid = threadIdx.x;
    int wid = tid >> 6, lane = tid & 63;
    int quad = lane >> 4, lr = lane & 15;
    int wm = (wid & 1) * 32, wn = (wid >> 1) * 64;
    int srow = tid >> 2;
    int schk = (tid & 3) * 8;

    floatx4 acc[2][4];
#pragma unroll
    for (int i = 0; i < 2; ++i)
#pragma unroll
        for (int j = 0; j < 4; ++j) { floatx4 zv = {0.f, 0.f, 0.f, 0.f}; acc[i][j] = zv; }

    for (int k0 = 0; k0 < Ka; k0 += BK) {
        float4 a0 = *(const float4*)(Ab + (size_t)(bm + srow) * Ka + k0 + schk);
        float4 w0 = *(const float4*)(Wg + (size_t)(bo + srow) * Ka + k0 + schk);
        float4 w1 = *(const float4*)(Wg + (size_t)(bo + srow + 64) * Ka + k0 + schk);
        __syncthreads();
        *(float4*)&As[srow * LDSS + schk] = a0;
        *(float4*)&Ws[srow * LDSS + schk] = w0;
        *(float4*)&Ws[(srow + 64) * LDSS + schk] = w1;
        __syncthreads();
        short8 af[2], bf[4];
#pragma unroll
        for (int mi = 0; mi < 2; ++mi)
            af[mi] = *(const short8*)&As[(wm + mi * 16 + lr) * LDSS + quad * 8];
#pragma unroll
        for (int ni = 0; ni < 4; ++ni)
            bf[ni] = *(const short8*)&Ws[(wn + ni * 16 + lr) * LDSS + quad * 8];
#pragma unroll
        for (int mi = 0; mi < 2; ++mi)
#pragma unroll
            for (int ni = 0; ni < 4; ++ni)
                acc[mi][ni] = __builtin_amdgcn_mfma_f32_16x16x32_bf16(
                    af[mi], bf[ni], acc[mi][ni], 0, 0, 0);
    }

#pragma unroll
    for (int mi = 0; mi < 2; ++mi) {
        int row0 = bm + wm + mi * 16 + quad * 4;
#pragma unroll
        for (int ni = 0; ni < 4; ++ni) {
            int col = bo + wn + ni * 16 + lr;
#pragma unroll
            for (int r = 0; r < 4; ++r) {
                float v = acc[mi][ni][r];
                size_t off = (size_t)(base + row0 + r) * Oc + col;
                if (epi == 2) C[off] = __float2bfloat16(sigmoidf_(v));
                else {
                    float a = __bfloat162float(aux[off]);
                    C[off] = __float2bfloat16(a * v);
                }
            }
        }
    }
}

// ---------------- sigmoid/sinkhorn per (expert, token) ----------------
__global__ __launch_bounds__(256) void mhc_post_kernel(
    const float* __restrict__ Cproj,
    const float* __restrict__ b_pre, const float* __restrict__ b_post,
    const float* __restrict__ b_res, const float* __restrict__ a_pre,
    const float* __restrict__ a_post, const float* __restrict__ a_res,
    float* __restrict__ Hpre, float* __restrict__ Hpost, float* __restrict__ Hres)
{
    int gid = blockIdx.x * 256 + threadIdx.x;
    int k = gid >> 11, bt = gid & 2047, e = k + 1;
    const float* s = Cproj + (size_t)bt * PHI_ROWS_P + k * 24;
    float ap = a_pre[e], aq = a_post[e], ar = a_res[e];
#pragma unroll
    for (int n = 0; n < 4; ++n)
        Hpre[((size_t)k * BT_TOT + bt) * 4 + n] = sigmoidf_(ap * s[n] + b_pre[e * 4 + n]);
#pragma unroll
    for (int n = 0; n < 4; ++n)
        Hpost[((size_t)k * BT_TOT + bt) * 4 + n] = 2.f * sigmoidf_(aq * s[4 + n] + b_post[e * 4 + n]);
    float M[16];
#pragma unroll
    for (int i = 0; i < 16; ++i) M[i] = expf(ar * s[8 + i] + b_res[e * 16 + i]);
#pragma unroll
    for (int it = 0; it < 6; ++it) {
#pragma unroll
        for (int i = 0; i < 4; ++i) {
            float iv = 1.f / (M[i*4] + M[i*4+1] + M[i*4+2] + M[i*4+3]);
            M[i*4] *= iv; M[i*4+1] *= iv; M[i*4+2] *= iv; M[i*4+3] *= iv;
        }
#pragma unroll
        for (int j = 0; j < 4; ++j) {
            float iv = 1.f / (M[j] + M[4+j] + M[8+j] + M[12+j]);
            M[j] *= iv; M[4+j] *= iv; M[8+j] *= iv; M[12+j] *= iv;
        }
    }
#pragma unroll
    for (int i = 0; i < 16; ++i) Hres[((size_t)k * BT_TOT + bt) * 16 + i] = M[i];
}

// ---------------- h (compacted) = rmsnorm(H_pre @ stream) * swiglu_norm ----------------
__global__ __launch_bounds__(256) void h_kernel(
    const float* __restrict__ stream, const float* __restrict__ Hpre,
    const float* __restrict__ sw_norm, const int* __restrict__ list,
    const int* __restrict__ counts, const int* __restrict__ offs,
    __hip_bfloat16* __restrict__ hA)
{
    int k = blockIdx.y;
    int i = blockIdx.x;
    if (i >= counts[k]) return;
    int bt = list[k * BT_TOT + i];
    int e = k + 1;
    int b = bt >> 10, t = bt & 1023;
    int tid = threadIdx.x;
    float hp[4];
#pragma unroll
    for (int n = 0; n < 4; ++n) hp[n] = Hpre[((size_t)k * BT_TOT + bt) * 4 + n];
    float he[2]; float ss = 0.f;
#pragma unroll
    for (int w = 0; w < 2; ++w) {
        int d = tid + w * 256;
        float v = 0.f;
#pragma unroll
        for (int n = 0; n < 4; ++n)
            v += hp[n] * stream[(((size_t)b * 4 + n) * T_LEN + t) * D_H + d];
        he[w] = v; ss += v * v;
    }
#pragma unroll
    for (int off = 32; off; off >>= 1) ss += __shfl_down(ss, off, 64);
    __shared__ float red[4];
    int wave = tid >> 6, lane = tid & 63;
    if (lane == 0) red[wave] = ss;
    __syncthreads();
    float tot = red[0] + red[1] + red[2] + red[3];
    float r = rsqrtf(tot / (float)D_H + 1e-8f);
    size_t row = (size_t)(offs[k] + i);
#pragma unroll
    for (int w = 0; w < 2; ++w) {
        int d = tid + w * 256;
        hA[row * D_H + d] = __float2bfloat16(he[w] * r * sw_norm[(size_t)e * D_H + d]);
    }
}

// ---------------- combine: out = sum_k gate*(H_res@stream + H_post*oute) ----------------
__global__ __launch_bounds__(256) void combine_kernel(
    const float* __restrict__ stream, const __hip_bfloat16* __restrict__ outeA,
    const float* __restrict__ Hpost, const float* __restrict__ Hres,
    const float* __restrict__ gate_all, const int* __restrict__ pos,
    const int* __restrict__ offs, float* __restrict__ out)
{
    int bt = blockIdx.x; int b = bt >> 10; int t = bt & 1023;
    int tid = threadIdx.x;
    float s[2][4], accv[2][4];
#pragma unroll
    for (int w = 0; w < 2; ++w) {
        int d = tid + w * 256;
#pragma unroll
        for (int n = 0; n < 4; ++n) {
            s[w][n] = stream[(((size_t)b * 4 + n) * T_LEN + t) * D_H + d];
            accv[w][n] = 0.f;
        }
    }
    for (int k = 0; k < KEXP; ++k) {
        float gate = gate_all[(size_t)bt * 16 + k + 1];
        if (gate == 0.f) continue;
        size_t row = (size_t)(offs[k] + pos[k * BT_TOT + bt]);
        float hr[16], hp[4];
#pragma unroll
        for (int i = 0; i < 16; ++i) hr[i] = Hres[((size_t)k * BT_TOT + bt) * 16 + i];
#pragma unroll
        for (int i = 0; i < 4; ++i) hp[i] = Hpost[((size_t)k * BT_TOT + bt) * 4 + i];
#pragma unroll
        for (int w = 0; w < 2; ++w) {
            int d = tid + w * 256;
            float oe = __bfloat162float(outeA[row * D_H + d]);
#pragma unroll
            for (int i = 0; i < 4; ++i) {
                float v = hp[i] * oe + hr[i*4+0]*s[w][0] + hr[i*4+1]*s[w][1]
                        + hr[i*4+2]*s[w][2] + hr[i*4+3]*s[w][3];
                accv[w][i] += gate * v;
            }
        }
    }
#pragma unroll
    for (int w = 0; w < 2; ++w) {
        int d = tid + w * 256;
#pragma unroll
        for (int i = 0; i < 4; ++i)
            out[(((size_t)b * 4 + i) * T_LEN + t) * D_H + d] = accv[w][i];
    }
}

extern "C" void kernel_launch(void* const* d_in, const int* in_sizes, int n_in,
                              void* d_out, int out_size, void* d_ws, size_t ws_size,
                              hipStream_t stream) {
    const float* stream_in = (const float*)d_in[0];
    const float* norm_w    = (const float*)d_in[1];
    const float* phi_pre   = (const float*)d_in[2];
    const float* phi_post  = (const float*)d_in[3];
    const float* phi_res   = (const float*)d_in[4];
    const float* b_pre     = (const float*)d_in[5];
    const float* b_post    = (const float*)d_in[6];
    const float* b_res     = (const float*)d_in[7];
    const float* alpha_pre = (const float*)d_in[8];
    const float* alpha_post= (const float*)d_in[9];
    const float* alpha_res = (const float*)d_in[10];
    const float* sw_norm   = (const float*)d_in[11];
    const float* wd_w      = (const float*)d_in[12];
    const float* wu_w      = (const float*)d_in[13];
    const float* gate_w    = (const float*)d_in[14];
    const float* up_w      = (const float*)d_in[15];
    const float* down_w    = (const float*)d_in[16];
    const float* router_w  = (const float*)d_in[17];

    float* out = (float*)d_out;
    const int SU_N = 2 * 4 * T_LEN * D_H;
    float* gate_out = out + SU_N;
    float* lp_out = gate_out + BT_TOT * 16;

    // ---- workspace carve-up ----
    char* p = (char*)d_ws;
    __hip_bfloat16* xn     = (__hip_bfloat16*)p; p += (size_t)BT_TOT * ND * 2;
    __hip_bfloat16* phiall = (__hip_bfloat16*)p; p += (size_t)PHI_ROWS_P * ND * 2;
    float* Cproj = (float*)p; p += (size_t)BT_TOT * PHI_ROWS_P * 4;
    float* Hpre  = (float*)p; p += (size_t)KEXP * BT_TOT * 4 * 4;
    float* Hpost = (float*)p; p += (size_t)KEXP * BT_TOT * 4 * 4;
    float* Hres  = (float*)p; p += (size_t)KEXP * BT_TOT * 16 * 4;
    int* cnt  = (int*)p; p += 256;
    int* offs = (int*)p; p += 256;
    int* list = (int*)p; p += (size_t)KEXP * BT_TOT * 4;
    int* pos  = (int*)p; p += (size_t)KEXP * BT_TOT * 4;
    __hip_bfloat16* hA    = (__hip_bfloat16*)p; p += (size_t)PAIR_CAP * D_H * 2;
    __hip_bfloat16* s1A   = (__hip_bfloat16*)p; p += (size_t)PAIR_CAP * D_H * 2;
    __hip_bfloat16* gA    = (__hip_bfloat16*)p; p += (size_t)PAIR_CAP * D_H * 2;
    __hip_bfloat16* outeA = (__hip_bfloat16*)p; p += (size_t)PAIR_CAP * D_H * 2;
    __hip_bfloat16* tA    = (__hip_bfloat16*)p; p += (size_t)PAIR_CAP * DFFN_P * 2;
    size_t fixed_bytes = (size_t)(p - (char*)d_ws);
    size_t perW = (size_t)EXPW * 2;
    size_t avail = ws_size > fixed_bytes ? ws_size - fixed_bytes : 0;
    int G = (int)(avail / perW);
    if (G > KEXP) G = KEXP;
    if (G < 1) G = 1;
    __hip_bfloat16* wbuf = (__hip_bfloat16*)p;

    // ---- prologue ----
    hipMemsetAsync(cnt, 0, 64, stream);
    hipMemsetAsync(Cproj, 0, (size_t)BT_TOT * PHI_ROWS_P * 4, stream);
    router_kernel<<<BT_TOT, 64, 0, stream>>>(
        stream_in, router_w, gate_out, lp_out, cnt, list, pos);
    scan_kernel<<<1, 64, 0, stream>>>(cnt, offs);
    xn_kernel<<<BT_TOT, 256, 0, stream>>>(stream_in, xn);
    cvt_phi_kernel<<<(PHI_ROWS_P * ND) / 256, 256, 0, stream>>>(
        norm_w, phi_pre, phi_post, phi_res, phiall);
    gemm_mfma<<<dim3(3, 16, 4), 256, 0, stream>>>(
        xn, phiall, Cproj, ND, PHI_ROWS_P, 512, 512);
    mhc_post_kernel<<<(KEXP * BT_TOT) / 256, 256, 0, stream>>>(
        Cproj, b_pre, b_post, b_res, alpha_pre, alpha_post, alpha_res, Hpre, Hpost, Hres);
    h_kernel<<<dim3(BT_TOT, KEXP), 256, 0, stream>>>(
        stream_in, Hpre, sw_norm, list, cnt, offs, hA);

    // ---- expert weight groups ----
    for (int kg = 0; kg < KEXP; kg += G) {
        int Gc = (kg + G <= KEXP) ? G : (KEXP - kg);
        int e0 = kg + 1;
        cvt_all_kernel<<<dim3(448, 5, Gc), 256, 0, stream>>>(
            wd_w, wu_w, gate_w, up_w, down_w, wbuf, e0);
        // s1 = silu(h@wd^T)  ||  t = silu(h@gate^T)*(h@up^T)
        gemm_fused<<<dim3(11, 16, Gc), 256, 0, stream>>>(
            hA, wbuf, s1A, tA, cnt, offs, kg);
        // g = sigmoid(s1 @ wu^T)
        gemm_mfma64<<<dim3(4, 32, Gc), 256, 0, stream>>>(
            s1A, wbuf, nullptr, gA, cnt, offs, kg, 512, 512, WU_OFF, 2);
        // oute = g * (t @ down^T)
        gemm_mfma64<<<dim3(4, 32, Gc), 256, 0, stream>>>(
            tA, wbuf, gA, outeA, cnt, offs, kg, DFFN_P, 512, DOWN_OFF, 3);
    }

    combine_kernel<<<BT_TOT, 256, 0, stream>>>(
        stream_in, outeA, Hpost, Hres, gate_out, pos, offs, out);
}

// Round 5
// 400.346 us; speedup vs baseline: 11.2342x; 1.1501x over previous
//
#include <hip/hip_runtime.h>
#include <hip/hip_bf16.h>
#include <math.h>

typedef __attribute__((ext_vector_type(8))) short short8;
typedef __attribute__((ext_vector_type(4))) float floatx4;

#define T_LEN 1024
#define D_H 512
#define ND 2048
#define KEXP 15
#define DFFN 828
#define DFFN_P 896
#define BT_TOT 2048
#define PHI_ROWS 360
#define PHI_ROWS_P 384
#define PAIR_CAP 9216   // sum of per-expert 64-rounded counts <= 8192+15*63

// per-expert packed bf16 weight layout (elements)
#define WD_OFF   0
#define WU_OFF   262144
#define GATE_OFF 524288
#define UP_OFF   983040
#define DOWN_OFF 1441792
#define EXPW     1900544

#define BK 32

__device__ __forceinline__ float sigmoidf_(float x) { return 1.f / (1.f + expf(-x)); }
__device__ __forceinline__ unsigned short bf16b_(float x) {
    __hip_bfloat16 h = __float2bfloat16(x);
    return *reinterpret_cast<unsigned short*>(&h);
}

// async global->LDS, 16B per lane; LDS dest = wave-uniform base + lane*16
__device__ __forceinline__ void gload16(const __hip_bfloat16* g, unsigned short* l) {
    __builtin_amdgcn_global_load_lds(
        (const __attribute__((address_space(1))) void*)(uintptr_t)g,
        (__attribute__((address_space(3))) void*)(unsigned int)(uintptr_t)l,
        16, 0, 0);
}

// ---------------- router + list build ----------------
__global__ __launch_bounds__(64) void router_kernel(
    const float* __restrict__ stream, const float* __restrict__ rw,
    float* __restrict__ gate_out, float* __restrict__ lp_out,
    int* __restrict__ cnt, int* __restrict__ list, int* __restrict__ pos)
{
    int bt = blockIdx.x; int b = bt >> 10; int t = bt & 1023;
    int lane = threadIdx.x;
    float ri[8];
#pragma unroll
    for (int w = 0; w < 8; ++w) {
        int d = lane + w * 64;
        float s = 0.f;
#pragma unroll
        for (int n = 0; n < 4; ++n)
            s += stream[(((size_t)b * 4 + n) * T_LEN + t) * D_H + d];
        ri[w] = 0.25f * s;
    }
    float logits[16];
    for (int e = 0; e < 16; ++e) {
        float p = 0.f;
#pragma unroll
        for (int w = 0; w < 8; ++w) p += ri[w] * rw[e * D_H + lane + w * 64];
#pragma unroll
        for (int off = 32; off; off >>= 1) p += __shfl_xor(p, off, 64);
        logits[e] = p;
    }
    float mx = logits[0];
    for (int e = 1; e < 16; ++e) mx = fmaxf(mx, logits[e]);
    float pr[16]; float sum = 0.f;
    for (int e = 0; e < 16; ++e) { pr[e] = expf(logits[e] - mx); sum += pr[e]; }
    float inv = 1.f / sum;
    for (int e = 0; e < 16; ++e) pr[e] *= inv;

    float gate[16]; bool taken[16];
    for (int e = 0; e < 16; ++e) { gate[e] = 0.f; taken[e] = false; }
    float prefix = 0.f;
    for (int rank = 0; rank < 4; ++rank) {
        int best = -1; float bp = -1.f;
        for (int e = 0; e < 16; ++e)
            if (!taken[e] && pr[e] > bp) { bp = pr[e]; best = e; }
        taken[best] = true;
        bool sel = (rank == 0) || (prefix < 0.8f);
        if (sel) gate[best] = bp;
        prefix += bp;
        if (!sel) break;
    }
    float lp = 0.f;
    for (int e = 0; e < 16; ++e)
        if (gate[e] > 0.f) lp += fmaxf(logf(pr[e]), -10.f);
    if (lane < 16) gate_out[(size_t)bt * 16 + lane] = gate[lane];
    if (lane == 0) lp_out[bt] = lp;
    if (lane >= 1 && lane < 16 && gate[lane] > 0.f) {
        int k = lane - 1;
        int p = atomicAdd(&cnt[k], 1);
        list[k * BT_TOT + p] = bt;
        pos[k * BT_TOT + bt] = p;
    }
}

// offsets rounded to 64 so GEMM tile tails never cross expert segments
__global__ void scan_kernel(const int* __restrict__ cnt, int* __restrict__ offs) {
    if (threadIdx.x == 0) {
        int a = 0;
        for (int k = 0; k < KEXP; ++k) { offs[k] = a; a += (cnt[k] + 63) & ~63; }
        offs[KEXP] = a;
    }
}

// ---------------- xn = rmsnorm(x) over nd=2048, bf16 out ----------------
__global__ __launch_bounds__(256) void xn_kernel(
    const float* __restrict__ stream, __hip_bfloat16* __restrict__ xn)
{
    int bt = blockIdx.x; int b = bt >> 10; int t = bt & 1023;
    int tid = threadIdx.x;
    float v[8]; float ss = 0.f;
#pragma unroll
    for (int w = 0; w < 8; ++w) {
        int j = tid + w * 256;
        int n = j >> 9, d = j & 511;
        float x = stream[(((size_t)b * 4 + n) * T_LEN + t) * D_H + d];
        v[w] = x; ss += x * x;
    }
#pragma unroll
    for (int off = 32; off; off >>= 1) ss += __shfl_down(ss, off, 64);
    __shared__ float red[4];
    int wave = tid >> 6, lane = tid & 63;
    if (lane == 0) red[wave] = ss;
    __syncthreads();
    float tot = red[0] + red[1] + red[2] + red[3];
    float r = rsqrtf(tot / (float)ND + 1e-8f);
#pragma unroll
    for (int w = 0; w < 8; ++w)
        xn[(size_t)bt * ND + tid + w * 256] = __float2bfloat16(v[w] * r);
}

// ---------------- phi_eff -> bf16 [384][2048], norm_w folded ----------------
__global__ __launch_bounds__(256) void cvt_phi_kernel(
    const float* __restrict__ norm_w, const float* __restrict__ phi_pre,
    const float* __restrict__ phi_post, const float* __restrict__ phi_res,
    __hip_bfloat16* __restrict__ phi_all)
{
    int idx = blockIdx.x * 256 + threadIdx.x;
    int row = idx >> 11, col = idx & 2047;
    float v = 0.f;
    if (row < PHI_ROWS) {
        int k = row / 24, j = row - k * 24, e = k + 1;
        float nw = norm_w[(size_t)e * ND + col];
        float p;
        if (j < 4)      p = phi_pre[((size_t)e * 4 + j) * ND + col];
        else if (j < 8) p = phi_post[((size_t)e * 4 + (j - 4)) * ND + col];
        else            p = phi_res[((size_t)e * 16 + (j - 8)) * ND + col];
        v = p * nw;
    }
    phi_all[idx] = __float2bfloat16(v);
}

// ---------------- single fused weight convert (all 5 types) ----------------
__global__ __launch_bounds__(256) void cvt_all_kernel(
    const float* __restrict__ wd, const float* __restrict__ wu,
    const float* __restrict__ gate, const float* __restrict__ up,
    const float* __restrict__ down, __hip_bfloat16* __restrict__ wbuf, int e0)
{
    int z = blockIdx.z;
    int type = blockIdx.y;
    int g = blockIdx.x * 256 + threadIdx.x;
    int e = e0 + z;
    __hip_bfloat16* dstb = wbuf + (size_t)z * EXPW;
    float4 v = make_float4(0.f, 0.f, 0.f, 0.f);
    size_t didx;
    if (type <= 1) {
        if (g >= 65536) return;
        didx = (type == 0 ? WD_OFF : WU_OFF) + (size_t)g * 4;
        const float* src = (type == 0 ? wd : wu) + (size_t)e * 262144;
        v = *(const float4*)(src + (size_t)g * 4);
    } else if (type <= 3) {
        if (g >= 114688) return;
        size_t idx4 = (size_t)g * 4;
        didx = (type == 2 ? GATE_OFF : UP_OFF) + idx4;
        if (idx4 < (size_t)DFFN * 512) {
            const float* src = (type == 2 ? gate : up) + (size_t)e * DFFN * 512;
            v = *(const float4*)(src + idx4);
        }
    } else {
        if (g >= 114688) return;
        int r = g / 224, gc = g - r * 224;
        didx = DOWN_OFF + (size_t)g * 4;
        if (gc < 207)
            v = *(const float4*)(down + (size_t)e * 512 * DFFN + (size_t)r * DFFN + gc * 4);
    }
    ushort4 o;
    o.x = bf16b_(v.x); o.y = bf16b_(v.y); o.z = bf16b_(v.z); o.w = bf16b_(v.w);
    *(ushort4*)((unsigned short*)dstb + didx) = o;
}

// ---------------- dense 128x128 MFMA GEMM (phi projections, split-K atomic) ----------------
#define LDSS 40
__global__ __launch_bounds__(256) void gemm_dense(
    const __hip_bfloat16* __restrict__ A, const __hip_bfloat16* __restrict__ W,
    float* __restrict__ Cf, int Ka, int Oc, int kLen, int kzStride)
{
    __shared__ __align__(16) unsigned short As[128 * LDSS];
    __shared__ __align__(16) unsigned short Ws[128 * LDSS];
    int z = blockIdx.z;
    int bo = blockIdx.x * 128;
    int bm = blockIdx.y * 128;
    int kbeg = z * kzStride;
    int tid = threadIdx.x;
    int wid = tid >> 6, lane = tid & 63;
    int quad = lane >> 4, lr = lane & 15;
    int wm = (wid & 1) * 64, wn = (wid >> 1) * 64;
    int srow = tid >> 2;
    int schk = (tid & 3) * 8;

    floatx4 acc[4][4];
#pragma unroll
    for (int i = 0; i < 4; ++i)
#pragma unroll
        for (int j = 0; j < 4; ++j) { floatx4 zv = {0.f, 0.f, 0.f, 0.f}; acc[i][j] = zv; }

    for (int k0 = kbeg; k0 < kbeg + kLen; k0 += BK) {
        float4 a0 = *(const float4*)(A + (size_t)(bm + srow) * Ka + k0 + schk);
        float4 a1 = *(const float4*)(A + (size_t)(bm + srow + 64) * Ka + k0 + schk);
        float4 w0 = *(const float4*)(W + (size_t)(bo + srow) * Ka + k0 + schk);
        float4 w1 = *(const float4*)(W + (size_t)(bo + srow + 64) * Ka + k0 + schk);
        __syncthreads();
        *(float4*)&As[srow * LDSS + schk] = a0;
        *(float4*)&As[(srow + 64) * LDSS + schk] = a1;
        *(float4*)&Ws[srow * LDSS + schk] = w0;
        *(float4*)&Ws[(srow + 64) * LDSS + schk] = w1;
        __syncthreads();
        short8 af[4], bf[4];
#pragma unroll
        for (int mi = 0; mi < 4; ++mi)
            af[mi] = *(const short8*)&As[(wm + mi * 16 + lr) * LDSS + quad * 8];
#pragma unroll
        for (int ni = 0; ni < 4; ++ni)
            bf[ni] = *(const short8*)&Ws[(wn + ni * 16 + lr) * LDSS + quad * 8];
#pragma unroll
        for (int mi = 0; mi < 4; ++mi)
#pragma unroll
            for (int ni = 0; ni < 4; ++ni)
                acc[mi][ni] = __builtin_amdgcn_mfma_f32_16x16x32_bf16(
                    af[mi], bf[ni], acc[mi][ni], 0, 0, 0);
    }
#pragma unroll
    for (int mi = 0; mi < 4; ++mi) {
        int row0 = bm + wm + mi * 16 + quad * 4;
#pragma unroll
        for (int ni = 0; ni < 4; ++ni) {
            int col = bo + wn + ni * 16 + lr;
#pragma unroll
            for (int r = 0; r < 4; ++r)
                atomicAdd(&Cf[(size_t)(row0 + r) * Oc + col], acc[mi][ni][r]);
        }
    }
}

// ---------------- stage A: s1 = silu(h@wd^T) || t = silu(h@gate^T)*(h@up^T) ----------------
// BM=64, BN=128, async global_load_lds staging, XOR-swizzled LDS (stride 32, no pad)
__global__ __launch_bounds__(256) void gemm_stage1(
    const __hip_bfloat16* __restrict__ hA, const __hip_bfloat16* __restrict__ wbuf,
    __hip_bfloat16* __restrict__ s1A, __hip_bfloat16* __restrict__ tA,
    const int* __restrict__ cnt, const int* __restrict__ offs, int kg)
{
    __shared__ __align__(16) unsigned short As[64 * 32];
    __shared__ __align__(16) unsigned short Gs[128 * 32];
    __shared__ __align__(16) unsigned short Us[128 * 32];
    int z = blockIdx.z;
    int k = kg + z;
    int bm = blockIdx.y * 64;
    if (bm >= cnt[k]) return;
    int base = offs[k];
    bool dual = (blockIdx.x >= 4);
    int bo = (dual ? (blockIdx.x - 4) : blockIdx.x) * 128;
    const __hip_bfloat16* Ab = hA + (size_t)base * D_H;
    const __hip_bfloat16* W1 = wbuf + (size_t)z * EXPW + (dual ? GATE_OFF : WD_OFF);
    const __hip_bfloat16* W2 = wbuf + (size_t)z * EXPW + UP_OFF;
    int tid = threadIdx.x;
    int wid = tid >> 6, lane = tid & 63;
    int quad = lane >> 4, lr = lane & 15;
    int lrow = lane >> 2, lchk = lane & 3;
    int achk = lchk ^ ((lrow >> 1) & 3);       // staging chunk swizzle
    int fs = quad ^ ((lr >> 1) & 3);           // fragment read swizzle
    int wm = (wid & 1) * 32, wn = (wid >> 1) * 64;

    floatx4 a1[2][4], a2[2][4];
#pragma unroll
    for (int i = 0; i < 2; ++i)
#pragma unroll
        for (int j = 0; j < 4; ++j) {
            floatx4 zv = {0.f, 0.f, 0.f, 0.f};
            a1[i][j] = zv; a2[i][j] = zv;
        }

    int sr0 = wid * 16 + lrow;
    int sr1 = (wid + 4) * 16 + lrow;
    const size_t aoff  = (size_t)(bm + sr0) * D_H + achk * 8;
    const size_t g0off = (size_t)(bo + sr0) * D_H + achk * 8;
    const size_t g1off = (size_t)(bo + sr1) * D_H + achk * 8;

    for (int k0 = 0; k0 < D_H; k0 += BK) {
        __syncthreads();
        gload16(Ab + aoff + k0, As + wid * 512);
        gload16(W1 + g0off + k0, Gs + wid * 512);
        gload16(W1 + g1off + k0, Gs + (wid + 4) * 512);
        if (dual) {
            gload16(W2 + g0off + k0, Us + wid * 512);
            gload16(W2 + g1off + k0, Us + (wid + 4) * 512);
        }
        __syncthreads();
        short8 af[2], bg[4];
#pragma unroll
        for (int mi = 0; mi < 2; ++mi)
            af[mi] = *(const short8*)&As[(wm + mi * 16 + lr) * 32 + fs * 8];
#pragma unroll
        for (int ni = 0; ni < 4; ++ni)
            bg[ni] = *(const short8*)&Gs[(wn + ni * 16 + lr) * 32 + fs * 8];
#pragma unroll
        for (int mi = 0; mi < 2; ++mi)
#pragma unroll
            for (int ni = 0; ni < 4; ++ni)
                a1[mi][ni] = __builtin_amdgcn_mfma_f32_16x16x32_bf16(
                    af[mi], bg[ni], a1[mi][ni], 0, 0, 0);
        if (dual) {
            short8 bu[4];
#pragma unroll
            for (int ni = 0; ni < 4; ++ni)
                bu[ni] = *(const short8*)&Us[(wn + ni * 16 + lr) * 32 + fs * 8];
#pragma unroll
            for (int mi = 0; mi < 2; ++mi)
#pragma unroll
                for (int ni = 0; ni < 4; ++ni)
                    a2[mi][ni] = __builtin_amdgcn_mfma_f32_16x16x32_bf16(
                        af[mi], bu[ni], a2[mi][ni], 0, 0, 0);
        }
    }

#pragma unroll
    for (int mi = 0; mi < 2; ++mi) {
        int row0 = bm + wm + mi * 16 + quad * 4;
#pragma unroll
        for (int ni = 0; ni < 4; ++ni) {
            int col = bo + wn + ni * 16 + lr;
#pragma unroll
            for (int r = 0; r < 4; ++r) {
                float v = a1[mi][ni][r];
                if (dual) {
                    float uu = a2[mi][ni][r];
                    tA[(size_t)(base + row0 + r) * DFFN_P + col] =
                        __float2bfloat16(v * sigmoidf_(v) * uu);
                } else {
                    s1A[(size_t)(base + row0 + r) * D_H + col] =
                        __float2bfloat16(v * sigmoidf_(v));
                }
            }
        }
    }
}

// ---------------- final: oute = sigmoid(s1@wu^T) * (t@down^T), two K-phases ----------------
__global__ __launch_bounds__(256) void gemm_final(
    const __hip_bfloat16* __restrict__ s1A, const __hip_bfloat16* __restrict__ tA,
    const __hip_bfloat16* __restrict__ wbuf, __hip_bfloat16* __restrict__ outeA,
    const int* __restrict__ cnt, const int* __restrict__ offs, int kg)
{
    __shared__ __align__(16) unsigned short As[64 * 32];
    __shared__ __align__(16) unsigned short Ws[128 * 32];
    int z = blockIdx.z;
    int k = kg + z;
    int bm = blockIdx.y * 64;
    if (bm >= cnt[k]) return;
    int base = offs[k];
    int bo = blockIdx.x * 128;
    const __hip_bfloat16* A1 = s1A + (size_t)base * D_H;
    const __hip_bfloat16* A2 = tA + (size_t)base * DFFN_P;
    const __hip_bfloat16* Wu = wbuf + (size_t)z * EXPW + WU_OFF;
    const __hip_bfloat16* Wd = wbuf + (size_t)z * EXPW + DOWN_OFF;
    int tid = threadIdx.x;
    int wid = tid >> 6, lane = tid & 63;
    int quad = lane >> 4, lr = lane & 15;
    int lrow = lane >> 2, lchk = lane & 3;
    int achk = lchk ^ ((lrow >> 1) & 3);
    int fs = quad ^ ((lr >> 1) & 3);
    int wm = (wid & 1) * 32, wn = (wid >> 1) * 64;
    int sr0 = wid * 16 + lrow;
    int sr1 = (wid + 4) * 16 + lrow;

    floatx4 accg[2][4], accd[2][4];
#pragma unroll
    for (int i = 0; i < 2; ++i)
#pragma unroll
        for (int j = 0; j < 4; ++j) {
            floatx4 zv = {0.f, 0.f, 0.f, 0.f};
            accg[i][j] = zv; accd[i][j] = zv;
        }

    // phase 1: g-acc over K=512 (s1 @ wu^T)
    for (int k0 = 0; k0 < D_H; k0 += BK) {
        __syncthreads();
        gload16(A1 + (size_t)(bm + sr0) * D_H + k0 + achk * 8, As + wid * 512);
        gload16(Wu + (size_t)(bo + sr0) * D_H + k0 + achk * 8, Ws + wid * 512);
        gload16(Wu + (size_t)(bo + sr1) * D_H + k0 + achk * 8, Ws + (wid + 4) * 512);
        __syncthreads();
        short8 af[2], bf[4];
#pragma unroll
        for (int mi = 0; mi < 2; ++mi)
            af[mi] = *(const short8*)&As[(wm + mi * 16 + lr) * 32 + fs * 8];
#pragma unroll
        for (int ni = 0; ni < 4; ++ni)
            bf[ni] = *(const short8*)&Ws[(wn + ni * 16 + lr) * 32 + fs * 8];
#pragma unroll
        for (int mi = 0; mi < 2; ++mi)
#pragma unroll
            for (int ni = 0; ni < 4; ++ni)
                accg[mi][ni] = __builtin_amdgcn_mfma_f32_16x16x32_bf16(
                    af[mi], bf[ni], accg[mi][ni], 0, 0, 0);
    }
    // phase 2: d-acc over K=896 (t @ down^T)
    for (int k0 = 0; k0 < DFFN_P; k0 += BK) {
        __syncthreads();
        gload16(A2 + (size_t)(bm + sr0) * DFFN_P + k0 + achk * 8, As + wid * 512);
        gload16(Wd + (size_t)(bo + sr0) * DFFN_P + k0 + achk * 8, Ws + wid * 512);
        gload16(Wd + (size_t)(bo + sr1) * DFFN_P + k0 + achk * 8, Ws + (wid + 4) * 512);
        __syncthreads();
        short8 af[2], bf[4];
#pragma unroll
        for (int mi = 0; mi < 2; ++mi)
            af[mi] = *(const short8*)&As[(wm + mi * 16 + lr) * 32 + fs * 8];
#pragma unroll
        for (int ni = 0; ni < 4; ++ni)
            bf[ni] = *(const short8*)&Ws[(wn + ni * 16 + lr) * 32 + fs * 8];
#pragma unroll
        for (int mi = 0; mi < 2; ++mi)
#pragma unroll
            for (int ni = 0; ni < 4; ++ni)
                accd[mi][ni] = __builtin_amdgcn_mfma_f32_16x16x32_bf16(
                    af[mi], bf[ni], accd[mi][ni], 0, 0, 0);
    }

#pragma unroll
    for (int mi = 0; mi < 2; ++mi) {
        int row0 = bm + wm + mi * 16 + quad * 4;
#pragma unroll
        for (int ni = 0; ni < 4; ++ni) {
            int col = bo + wn + ni * 16 + lr;
#pragma unroll
            for (int r = 0; r < 4; ++r) {
                float g = accg[mi][ni][r];
                float d = accd[mi][ni][r];
                outeA[(size_t)(base + row0 + r) * D_H + col] =
                    __float2bfloat16(sigmoidf_(g) * d);
            }
        }
    }
}

// ---------------- sigmoid/sinkhorn per (expert, token) ----------------
__global__ __launch_bounds__(256) void mhc_post_kernel(
    const float* __restrict__ Cproj,
    const float* __restrict__ b_pre, const float* __restrict__ b_post,
    const float* __restrict__ b_res, const float* __restrict__ a_pre,
    const float* __restrict__ a_post, const float* __restrict__ a_res,
    float* __restrict__ Hpre, float* __restrict__ Hpost, float* __restrict__ Hres)
{
    int gid = blockIdx.x * 256 + threadIdx.x;
    int k = gid >> 11, bt = gid & 2047, e = k + 1;
    const float* s = Cproj + (size_t)bt * PHI_ROWS_P + k * 24;
    float ap = a_pre[e], aq = a_post[e], ar = a_res[e];
#pragma unroll
    for (int n = 0; n < 4; ++n)
        Hpre[((size_t)k * BT_TOT + bt) * 4 + n] = sigmoidf_(ap * s[n] + b_pre[e * 4 + n]);
#pragma unroll
    for (int n = 0; n < 4; ++n)
        Hpost[((size_t)k * BT_TOT + bt) * 4 + n] = 2.f * sigmoidf_(aq * s[4 + n] + b_post[e * 4 + n]);
    float M[16];
#pragma unroll
    for (int i = 0; i < 16; ++i) M[i] = expf(ar * s[8 + i] + b_res[e * 16 + i]);
#pragma unroll
    for (int it = 0; it < 6; ++it) {
#pragma unroll
        for (int i = 0; i < 4; ++i) {
            float iv = 1.f / (M[i*4] + M[i*4+1] + M[i*4+2] + M[i*4+3]);
            M[i*4] *= iv; M[i*4+1] *= iv; M[i*4+2] *= iv; M[i*4+3] *= iv;
        }
#pragma unroll
        for (int j = 0; j < 4; ++j) {
            float iv = 1.f / (M[j] + M[4+j] + M[8+j] + M[12+j]);
            M[j] *= iv; M[4+j] *= iv; M[8+j] *= iv; M[12+j] *= iv;
        }
    }
#pragma unroll
    for (int i = 0; i < 16; ++i) Hres[((size_t)k * BT_TOT + bt) * 16 + i] = M[i];
}

// ---------------- h (compacted) = rmsnorm(H_pre @ stream) * swiglu_norm ----------------
__global__ __launch_bounds__(256) void h_kernel(
    const float* __restrict__ stream, const float* __restrict__ Hpre,
    const float* __restrict__ sw_norm, const int* __restrict__ list,
    const int* __restrict__ counts, const int* __restrict__ offs,
    __hip_bfloat16* __restrict__ hA)
{
    int k = blockIdx.y;
    int i = blockIdx.x;
    if (i >= counts[k]) return;
    int bt = list[k * BT_TOT + i];
    int e = k + 1;
    int b = bt >> 10, t = bt & 1023;
    int tid = threadIdx.x;
    float hp[4];
#pragma unroll
    for (int n = 0; n < 4; ++n) hp[n] = Hpre[((size_t)k * BT_TOT + bt) * 4 + n];
    float he[2]; float ss = 0.f;
#pragma unroll
    for (int w = 0; w < 2; ++w) {
        int d = tid + w * 256;
        float v = 0.f;
#pragma unroll
        for (int n = 0; n < 4; ++n)
            v += hp[n] * stream[(((size_t)b * 4 + n) * T_LEN + t) * D_H + d];
        he[w] = v; ss += v * v;
    }
#pragma unroll
    for (int off = 32; off; off >>= 1) ss += __shfl_down(ss, off, 64);
    __shared__ float red[4];
    int wave = tid >> 6, lane = tid & 63;
    if (lane == 0) red[wave] = ss;
    __syncthreads();
    float tot = red[0] + red[1] + red[2] + red[3];
    float r = rsqrtf(tot / (float)D_H + 1e-8f);
    size_t row = (size_t)(offs[k] + i);
#pragma unroll
    for (int w = 0; w < 2; ++w) {
        int d = tid + w * 256;
        hA[row * D_H + d] = __float2bfloat16(he[w] * r * sw_norm[(size_t)e * D_H + d]);
    }
}

// ---------------- combine: out = sum_k gate*(H_res@stream + H_post*oute) ----------------
__global__ __launch_bounds__(256) void combine_kernel(
    const float* __restrict__ stream, const __hip_bfloat16* __restrict__ outeA,
    const float* __restrict__ Hpost, const float* __restrict__ Hres,
    const float* __restrict__ gate_all, const int* __restrict__ pos,
    const int* __restrict__ offs, float* __restrict__ out)
{
    int bt = blockIdx.x; int b = bt >> 10; int t = bt & 1023;
    int tid = threadIdx.x;
    float s[2][4], accv[2][4];
#pragma unroll
    for (int w = 0; w < 2; ++w) {
        int d = tid + w * 256;
#pragma unroll
        for (int n = 0; n < 4; ++n) {
            s[w][n] = stream[(((size_t)b * 4 + n) * T_LEN + t) * D_H + d];
            accv[w][n] = 0.f;
        }
    }
    for (int k = 0; k < KEXP; ++k) {
        float gate = gate_all[(size_t)bt * 16 + k + 1];
        if (gate == 0.f) continue;
        size_t row = (size_t)(offs[k] + pos[k * BT_TOT + bt]);
        float hr[16], hp[4];
#pragma unroll
        for (int i = 0; i < 16; ++i) hr[i] = Hres[((size_t)k * BT_TOT + bt) * 16 + i];
#pragma unroll
        for (int i = 0; i < 4; ++i) hp[i] = Hpost[((size_t)k * BT_TOT + bt) * 4 + i];
#pragma unroll
        for (int w = 0; w < 2; ++w) {
            int d = tid + w * 256;
            float oe = __bfloat162float(outeA[row * D_H + d]);
#pragma unroll
            for (int i = 0; i < 4; ++i) {
                float v = hp[i] * oe + hr[i*4+0]*s[w][0] + hr[i*4+1]*s[w][1]
                        + hr[i*4+2]*s[w][2] + hr[i*4+3]*s[w][3];
                accv[w][i] += gate * v;
            }
        }
    }
#pragma unroll
    for (int w = 0; w < 2; ++w) {
        int d = tid + w * 256;
#pragma unroll
        for (int i = 0; i < 4; ++i)
            out[(((size_t)b * 4 + i) * T_LEN + t) * D_H + d] = accv[w][i];
    }
}

extern "C" void kernel_launch(void* const* d_in, const int* in_sizes, int n_in,
                              void* d_out, int out_size, void* d_ws, size_t ws_size,
                              hipStream_t stream) {
    const float* stream_in = (const float*)d_in[0];
    const float* norm_w    = (const float*)d_in[1];
    const float* phi_pre   = (const float*)d_in[2];
    const float* phi_post  = (const float*)d_in[3];
    const float* phi_res   = (const float*)d_in[4];
    const float* b_pre     = (const float*)d_in[5];
    const float* b_post    = (const float*)d_in[6];
    const float* b_res     = (const float*)d_in[7];
    const float* alpha_pre = (const float*)d_in[8];
    const float* alpha_post= (const float*)d_in[9];
    const float* alpha_res = (const float*)d_in[10];
    const float* sw_norm   = (const float*)d_in[11];
    const float* wd_w      = (const float*)d_in[12];
    const float* wu_w      = (const float*)d_in[13];
    const float* gate_w    = (const float*)d_in[14];
    const float* up_w      = (const float*)d_in[15];
    const float* down_w    = (const float*)d_in[16];
    const float* router_w  = (const float*)d_in[17];

    float* out = (float*)d_out;
    const int SU_N = 2 * 4 * T_LEN * D_H;
    float* gate_out = out + SU_N;
    float* lp_out = gate_out + BT_TOT * 16;

    // ---- workspace carve-up ----
    char* p = (char*)d_ws;
    __hip_bfloat16* xn     = (__hip_bfloat16*)p; p += (size_t)BT_TOT * ND * 2;
    __hip_bfloat16* phiall = (__hip_bfloat16*)p; p += (size_t)PHI_ROWS_P * ND * 2;
    float* Cproj = (float*)p; p += (size_t)BT_TOT * PHI_ROWS_P * 4;
    float* Hpre  = (float*)p; p += (size_t)KEXP * BT_TOT * 4 * 4;
    float* Hpost = (float*)p; p += (size_t)KEXP * BT_TOT * 4 * 4;
    float* Hres  = (float*)p; p += (size_t)KEXP * BT_TOT * 16 * 4;
    int* cnt  = (int*)p; p += 256;
    int* offs = (int*)p; p += 256;
    int* list = (int*)p; p += (size_t)KEXP * BT_TOT * 4;
    int* pos  = (int*)p; p += (size_t)KEXP * BT_TOT * 4;
    __hip_bfloat16* hA    = (__hip_bfloat16*)p; p += (size_t)PAIR_CAP * D_H * 2;
    __hip_bfloat16* s1A   = (__hip_bfloat16*)p; p += (size_t)PAIR_CAP * D_H * 2;
    __hip_bfloat16* outeA = (__hip_bfloat16*)p; p += (size_t)PAIR_CAP * D_H * 2;
    __hip_bfloat16* tA    = (__hip_bfloat16*)p; p += (size_t)PAIR_CAP * DFFN_P * 2;
    size_t fixed_bytes = (size_t)(p - (char*)d_ws);
    size_t perW = (size_t)EXPW * 2;
    size_t avail = ws_size > fixed_bytes ? ws_size - fixed_bytes : 0;
    int G = (int)(avail / perW);
    if (G > KEXP) G = KEXP;
    if (G < 1) G = 1;
    __hip_bfloat16* wbuf = (__hip_bfloat16*)p;

    // ---- prologue ----
    hipMemsetAsync(cnt, 0, 64, stream);
    hipMemsetAsync(Cproj, 0, (size_t)BT_TOT * PHI_ROWS_P * 4, stream);
    router_kernel<<<BT_TOT, 64, 0, stream>>>(
        stream_in, router_w, gate_out, lp_out, cnt, list, pos);
    scan_kernel<<<1, 64, 0, stream>>>(cnt, offs);
    xn_kernel<<<BT_TOT, 256, 0, stream>>>(stream_in, xn);
    cvt_phi_kernel<<<(PHI_ROWS_P * ND) / 256, 256, 0, stream>>>(
        norm_w, phi_pre, phi_post, phi_res, phiall);
    gemm_dense<<<dim3(3, 16, 4), 256, 0, stream>>>(
        xn, phiall, Cproj, ND, PHI_ROWS_P, 512, 512);
    mhc_post_kernel<<<(KEXP * BT_TOT) / 256, 256, 0, stream>>>(
        Cproj, b_pre, b_post, b_res, alpha_pre, alpha_post, alpha_res, Hpre, Hpost, Hres);
    h_kernel<<<dim3(BT_TOT, KEXP), 256, 0, stream>>>(
        stream_in, Hpre, sw_norm, list, cnt, offs, hA);

    // ---- expert weight groups ----
    for (int kg = 0; kg < KEXP; kg += G) {
        int Gc = (kg + G <= KEXP) ? G : (KEXP - kg);
        int e0 = kg + 1;
        cvt_all_kernel<<<dim3(448, 5, Gc), 256, 0, stream>>>(
            wd_w, wu_w, gate_w, up_w, down_w, wbuf, e0);
        // s1 = silu(h@wd^T)  ||  t = silu(h@gate^T)*(h@up^T)
        gemm_stage1<<<dim3(11, 32, Gc), 256, 0, stream>>>(
            hA, wbuf, s1A, tA, cnt, offs, kg);
        // oute = sigmoid(s1@wu^T) * (t@down^T)
        gemm_final<<<dim3(4, 32, Gc), 256, 0, stream>>>(
            s1A, tA, wbuf, outeA, cnt, offs, kg);
    }

    combine_kernel<<<BT_TOT, 256, 0, stream>>>(
        stream_in, outeA, Hpost, Hres, gate_out, pos, offs, out);
}